// Round 9
// baseline (629.550 us; speedup 1.0000x reference)
//
#include <hip/hip_runtime.h>

typedef unsigned short u16;
typedef __attribute__((ext_vector_type(8))) short short8;
typedef __attribute__((ext_vector_type(4))) float f32x4;
typedef __attribute__((ext_vector_type(4))) unsigned short us4;
typedef __attribute__((ext_vector_type(8))) unsigned short us8;

#define N_NODES 50000
#define N_EDGES 800000
#define DIM 128
#define SCAN_B 196   /* ceil(50000/256) */
#define NINV (1.0f / 50000.0f)

__device__ __forceinline__ float bf2f(u16 u) {
    union { unsigned int i; float f; } v; v.i = ((unsigned int)u) << 16; return v.f;
}
__device__ __forceinline__ u16 f2bf(float f) {
    union { float f; unsigned int i; } v; v.f = f;
    return (u16)((v.i + 0x7FFFu + ((v.i >> 16) & 1u)) >> 16);
}

// ---------------- CSR build ----------------

__global__ void k_deg_hist(const int* __restrict__ dst, int* __restrict__ deg) {
    int e = blockIdx.x * 256 + threadIdx.x;
    if (e < N_EDGES) atomicAdd(&deg[dst[e]], 1);
}

__global__ void k_scan1(const int* __restrict__ deg, int* __restrict__ bsum) {
    __shared__ int sd[256];
    int t = threadIdx.x; int i = blockIdx.x * 256 + t;
    sd[t] = (i < N_NODES) ? deg[i] : 0;
    __syncthreads();
    for (int o = 128; o > 0; o >>= 1) { if (t < o) sd[t] += sd[t + o]; __syncthreads(); }
    if (t == 0) bsum[blockIdx.x] = sd[0];
}

__global__ void k_scan2(const int* __restrict__ bsum, int* __restrict__ bpre) {
    __shared__ int sd[256];
    int t = threadIdx.x;
    int v = (t < SCAN_B) ? bsum[t] : 0;
    sd[t] = v; __syncthreads();
    for (int o = 1; o < 256; o <<= 1) {
        int x = sd[t] + ((t >= o) ? sd[t - o] : 0);
        __syncthreads(); sd[t] = x; __syncthreads();
    }
    if (t < SCAN_B) bpre[t] = sd[t] - v;   // exclusive
}

// writes row_ptr AND cursor (cursor starts at row start; k_fill bumps it)
__global__ void k_scan3(const int* __restrict__ deg, const int* __restrict__ bpre,
                        int* __restrict__ row_ptr, int* __restrict__ cursor) {
    __shared__ int sd[256];
    int t = threadIdx.x; int i = blockIdx.x * 256 + t;
    int v = (i < N_NODES) ? deg[i] : 0;
    sd[t] = v; __syncthreads();
    for (int o = 1; o < 256; o <<= 1) {
        int x = sd[t] + ((t >= o) ? sd[t - o] : 0);
        __syncthreads(); sd[t] = x; __syncthreads();
    }
    if (i <= N_NODES) {
        int rp = bpre[blockIdx.x] + sd[t] - v;   // i==N gets E
        row_ptr[i] = rp;
        if (i < N_NODES) cursor[i] = rp;
    }
}

__global__ void k_fill(const int* __restrict__ src, const int* __restrict__ dst,
                       int* __restrict__ cursor, u16* __restrict__ col_src) {
    int e = blockIdx.x * 256 + threadIdx.x;
    if (e < N_EDGES) {
        int pos = atomicAdd(&cursor[dst[e]], 1);
        col_src[pos] = (u16)src[e];
    }
}

// ---------------- fp32 -> bf16 hi plane ----------------
__global__ __launch_bounds__(256) void k_split(
        const float* __restrict__ x, u16* __restrict__ xh) {
    long i4 = ((long)blockIdx.x * 256 + threadIdx.x) * 4;
    f32x4 v = *(const f32x4*)(x + i4);
    us4 h;
    #pragma unroll
    for (int j = 0; j < 4; ++j) h[j] = f2bf(v[j]);
    *(us4*)(xh + i4) = h;
}

// ---------------- aggregation: mean of source rows (bf16 in/out) ----------------
// 16 lanes per node, 16B (8 dims) per lane; 4x unrolled.
__global__ __launch_bounds__(256) void k_agg(
        const u16* __restrict__ fh,
        const int* __restrict__ row_ptr, const u16* __restrict__ col_src,
        u16* __restrict__ oh) {
    int tid = threadIdx.x;
    int grp = tid >> 4;          // 0..15
    int g   = tid & 15;
    int node = blockIdx.x * 16 + grp;    // grid 3125 -> exactly 50000
    int s = row_ptr[node], e = row_ptr[node + 1];
    int d8 = g * 8;
    float sum[8] = {0.f, 0.f, 0.f, 0.f, 0.f, 0.f, 0.f, 0.f};
    int j = s;
    for (; j + 4 <= e; j += 4) {
        int i0 = col_src[j], i1 = col_src[j + 1], i2 = col_src[j + 2], i3 = col_src[j + 3];
        us8 h0 = *(const us8*)(fh + (long)i0 * DIM + d8);
        us8 h1 = *(const us8*)(fh + (long)i1 * DIM + d8);
        us8 h2 = *(const us8*)(fh + (long)i2 * DIM + d8);
        us8 h3 = *(const us8*)(fh + (long)i3 * DIM + d8);
        #pragma unroll
        for (int k = 0; k < 8; ++k)
            sum[k] += (bf2f(h0[k]) + bf2f(h1[k])) + (bf2f(h2[k]) + bf2f(h3[k]));
    }
    for (; j < e; ++j) {
        int i0 = col_src[j];
        us8 h0 = *(const us8*)(fh + (long)i0 * DIM + d8);
        #pragma unroll
        for (int k = 0; k < 8; ++k) sum[k] += bf2f(h0[k]);
    }
    float dn = (e > s) ? 1.f / (float)(e - s) : 1.f;
    us8 rh;
    #pragma unroll
    for (int k = 0; k < 8; ++k) rh[k] = f2bf(sum[k] * dn);
    *(us8*)(oh + (long)node * DIM + d8) = rh;
}

// ---------------- B packing for MFMA fragment order ----------------
// Bp[((nt*8+kc)*64 + lane)*8 + j] = B[kc*32 + (lane>>4)*8 + j][nt*16 + (lane&15)]
__global__ void k_pack_b(const float* __restrict__ Wl, const float* __restrict__ Wr,
                         u16* __restrict__ Bph) {
    int idx = blockIdx.x * 256 + threadIdx.x;        // 4096 total
    if (idx >= 8 * 8 * 64) return;
    int lane = idx & 63;
    int kc = (idx >> 6) & 7;
    int nt = idx >> 9;
    int q = lane >> 4, nn = lane & 15;
    int col = nt * 16 + nn;
    #pragma unroll
    for (int j = 0; j < 8; ++j) {
        int k = kc * 32 + q * 8 + j;
        float v = (k < 128) ? Wl[k * 128 + col] : Wr[(k - 128) * 128 + col];
        Bph[(long)idx * 8 + j] = f2bf(v);
    }
}

// ---------------- fused GEMM + BN column stats, 1-wave blocks ----------------
// out = [Agg | Root](N x 256) @ B(256 x 128) + bias; stats: 64B-strided col sums/sumsq.
// Wave = block = 16 rows x 128 cols; grid 3125 (A read exactly once, fine dispatch grain).
// Stats: shuffle-reduce over q, q==0 lanes atomicAdd to stats[col*16] / stats[2048+col*16].
__global__ __launch_bounds__(64) void k_gemm(
        const u16* __restrict__ AggH, const u16* __restrict__ RootH,
        const u16* __restrict__ Bph, const float* __restrict__ bias,
        float* __restrict__ outH, float* __restrict__ stats) {
    int lane = threadIdx.x;
    int q = lane >> 4, nn = lane & 15;
    int rowbase = blockIdx.x * 16;       // 3125*16 == 50000 exact, no bounds checks
    long rc = rowbase + nn;

    f32x4 acc[8];
    #pragma unroll
    for (int i = 0; i < 8; ++i) acc[i] = (f32x4){0.f, 0.f, 0.f, 0.f};

    #pragma unroll
    for (int kc = 0; kc < 8; ++kc) {
        const u16* ph = (kc < 4) ? AggH : RootH;
        int ko = (kc & 3) * 32 + q * 8;
        short8 ah = *(const short8*)(ph + rc * DIM + ko);
        #pragma unroll
        for (int nt = 0; nt < 8; ++nt) {
            short8 bh = *(const short8*)(Bph + (((nt * 8 + kc) * 64 + lane) << 3));
            acc[nt] = __builtin_amdgcn_mfma_f32_16x16x32_bf16(ah, bh, acc[nt], 0, 0, 0);
        }
    }

    #pragma unroll
    for (int nt = 0; nt < 8; ++nt) {
        int col = nt * 16 + nn;
        float bv = bias[col];
        float ps = 0.f, pq = 0.f;
        #pragma unroll
        for (int r = 0; r < 4; ++r) {
            float v = acc[nt][r] + bv;
            outH[(long)(rowbase + q * 4 + r) * DIM + col] = v;
            ps += v; pq += v * v;
        }
        ps += __shfl_xor(ps, 16);
        ps += __shfl_xor(ps, 32);
        pq += __shfl_xor(pq, 16);
        pq += __shfl_xor(pq, 32);
        if (q == 0) {
            atomicAdd(&stats[col * 16], ps);
            atomicAdd(&stats[2048 + col * 16], pq);
        }
    }
}

// ---------------- BN apply (stats are 64B-strided: sum at c*16, sumsq at 2048+c*16) ----------------

// h1r = relu(bn(h)); writes bf16 hi plane (consumed by agg2 + gemm2 root)
__global__ __launch_bounds__(256) void k_bn_relu(
        const float* __restrict__ h, const float* __restrict__ stats,
        const float* __restrict__ g, const float* __restrict__ bt,
        u16* __restrict__ oh) {
    long i4 = ((long)blockIdx.x * 256 + threadIdx.x) * 4;
    int c = (int)(i4 & 127);
    f32x4 hv = *(const f32x4*)(h + i4);
    f32x4 gv = *(const f32x4*)(g + c);
    f32x4 bv = *(const f32x4*)(bt + c);
    us4 rh;
    #pragma unroll
    for (int j = 0; j < 4; ++j) {
        int cc = c + j;
        float mu = stats[cc * 16] * NINV;
        float var = stats[2048 + cc * 16] * NINV - mu * mu;
        float a = gv[j] * rsqrtf(var + 1e-5f);
        float v = (hv[j] - mu) * a + bv[j];
        v = v > 0.f ? v : 0.f;
        rh[j] = f2bf(v);
    }
    *(us4*)(oh + i4) = rh;
}

// out = relu(bn(h) + x), fp32
__global__ __launch_bounds__(256) void k_bn_add_relu(
        const float* __restrict__ h, const float* __restrict__ stats,
        const float* __restrict__ g, const float* __restrict__ bt,
        const float* __restrict__ x, float* __restrict__ outv) {
    long i4 = ((long)blockIdx.x * 256 + threadIdx.x) * 4;
    int c = (int)(i4 & 127);
    f32x4 hv = *(const f32x4*)(h + i4);
    f32x4 xv = *(const f32x4*)(x + i4);
    f32x4 gv = *(const f32x4*)(g + c);
    f32x4 bv = *(const f32x4*)(bt + c);
    f32x4 r;
    #pragma unroll
    for (int j = 0; j < 4; ++j) {
        int cc = c + j;
        float mu = stats[cc * 16] * NINV;
        float var = stats[2048 + cc * 16] * NINV - mu * mu;
        float a = gv[j] * rsqrtf(var + 1e-5f);
        float v = (hv[j] - mu) * a + bv[j] + xv[j];
        r[j] = v > 0.f ? v : 0.f;
    }
    *(f32x4*)(outv + i4) = r;
}

extern "C" void kernel_launch(void* const* d_in, const int* in_sizes, int n_in,
                              void* d_out, int out_size, void* d_ws, size_t ws_size,
                              hipStream_t stream) {
    (void)in_sizes; (void)n_in; (void)out_size; (void)ws_size;
    const float* x   = (const float*)d_in[0];
    const int*   ei  = (const int*)d_in[1];
    const float* W1l = (const float*)d_in[2];
    const float* b1  = (const float*)d_in[3];
    const float* W1r = (const float*)d_in[4];
    const float* g1  = (const float*)d_in[5];
    const float* bt1 = (const float*)d_in[6];
    const float* W2l = (const float*)d_in[7];
    const float* b2  = (const float*)d_in[8];
    const float* W2r = (const float*)d_in[9];
    const float* g2  = (const float*)d_in[10];
    const float* bt2 = (const float*)d_in[11];
    float* out = (float*)d_out;

    const int* esrc = ei;
    const int* edst = ei + N_EDGES;

    char* ws = (char*)d_ws;
    size_t off = 0;
    auto alloc = [&](size_t bytes) { size_t p = off; off = (off + bytes + 255) & ~(size_t)255; return p; };
    int*   deg     = (int*)  (ws + alloc(N_NODES * 4));
    float* stats1  = (float*)(ws + alloc(4096 * 4));   // 16 KB, 64B-strided sums/sumsq
    float* stats2  = (float*)(ws + alloc(4096 * 4));
    size_t zero_bytes = off;                       // everything above must be zeroed
    int*   cursor  = (int*)  (ws + alloc(N_NODES * 4));
    int*   row_ptr = (int*)  (ws + alloc((N_NODES + 1) * 4));
    int*   bsum    = (int*)  (ws + alloc(256 * 4));
    int*   bpre    = (int*)  (ws + alloc(256 * 4));
    u16*   col_src = (u16*)  (ws + alloc((size_t)N_EDGES * 2));
    u16*   xh      = (u16*)  (ws + alloc((size_t)N_NODES * DIM * 2));  // reused as h1r hi
    u16*   aggh    = (u16*)  (ws + alloc((size_t)N_NODES * DIM * 2));
    float* hbuf    = (float*)(ws + alloc((size_t)N_NODES * DIM * 4));
    u16*   Bp1h    = (u16*)  (ws + alloc(256 * 128 * 2));
    u16*   Bp2h    = (u16*)  (ws + alloc(256 * 128 * 2));

    hipMemsetAsync(ws, 0, zero_bytes, stream);

    const int EB = (N_EDGES + 255) / 256;            // 3125
    const int GEMMB = N_NODES / 16;                  // 3125 exact, 64-thr blocks
    const int AGGB = N_NODES / 16;                   // 3125 exact
    const int EWB4 = (int)(((long)N_NODES * DIM) / 1024);  // 6250 exact

    // weight packing + x hi-plane (independent of CSR)
    k_pack_b<<<16, 256, 0, stream>>>(W1l, W1r, Bp1h);
    k_pack_b<<<16, 256, 0, stream>>>(W2l, W2r, Bp2h);
    k_split<<<EWB4, 256, 0, stream>>>(x, xh);

    // CSR build
    k_deg_hist<<<EB, 256, 0, stream>>>(edst, deg);
    k_scan1<<<SCAN_B, 256, 0, stream>>>(deg, bsum);
    k_scan2<<<1, 256, 0, stream>>>(bsum, bpre);
    k_scan3<<<SCAN_B, 256, 0, stream>>>(deg, bpre, row_ptr, cursor);
    k_fill<<<EB, 256, 0, stream>>>(esrc, edst, cursor, col_src);

    // stage 1
    k_agg<<<AGGB, 256, 0, stream>>>(xh, row_ptr, col_src, aggh);
    k_gemm<<<GEMMB, 64, 0, stream>>>(aggh, xh, Bp1h, b1, hbuf, stats1);
    k_bn_relu<<<EWB4, 256, 0, stream>>>(hbuf, stats1, g1, bt1, xh);  // xh now holds h1r hi

    // stage 2
    k_agg<<<AGGB, 256, 0, stream>>>(xh, row_ptr, col_src, aggh);
    k_gemm<<<GEMMB, 64, 0, stream>>>(aggh, xh, Bp2h, b2, hbuf, stats2);
    k_bn_add_relu<<<EWB4, 256, 0, stream>>>(hbuf, stats2, g2, bt2, x, out);
}

// Round 10
// 342.874 us; speedup vs baseline: 1.8361x; 1.8361x over previous
//
#include <hip/hip_runtime.h>

typedef unsigned short u16;
typedef __attribute__((ext_vector_type(8))) short short8;
typedef __attribute__((ext_vector_type(4))) float f32x4;
typedef __attribute__((ext_vector_type(4))) unsigned short us4;
typedef __attribute__((ext_vector_type(8))) unsigned short us8;

#define N_NODES 50000
#define N_EDGES 800000
#define DIM 128
#define SCAN_B 196   /* ceil(50000/256) */
#define NINV (1.0f / 50000.0f)

__device__ __forceinline__ float bf2f(u16 u) {
    union { unsigned int i; float f; } v; v.i = ((unsigned int)u) << 16; return v.f;
}
__device__ __forceinline__ u16 f2bf(float f) {
    union { float f; unsigned int i; } v; v.f = f;
    return (u16)((v.i + 0x7FFFu + ((v.i >> 16) & 1u)) >> 16);
}

// ---------------- CSR build ----------------

__global__ void k_deg_hist(const int* __restrict__ dst, int* __restrict__ deg) {
    int e = blockIdx.x * 256 + threadIdx.x;
    if (e < N_EDGES) atomicAdd(&deg[dst[e]], 1);
}

__global__ void k_scan1(const int* __restrict__ deg, int* __restrict__ bsum) {
    __shared__ int sd[256];
    int t = threadIdx.x; int i = blockIdx.x * 256 + t;
    sd[t] = (i < N_NODES) ? deg[i] : 0;
    __syncthreads();
    for (int o = 128; o > 0; o >>= 1) { if (t < o) sd[t] += sd[t + o]; __syncthreads(); }
    if (t == 0) bsum[blockIdx.x] = sd[0];
}

__global__ void k_scan2(const int* __restrict__ bsum, int* __restrict__ bpre) {
    __shared__ int sd[256];
    int t = threadIdx.x;
    int v = (t < SCAN_B) ? bsum[t] : 0;
    sd[t] = v; __syncthreads();
    for (int o = 1; o < 256; o <<= 1) {
        int x = sd[t] + ((t >= o) ? sd[t - o] : 0);
        __syncthreads(); sd[t] = x; __syncthreads();
    }
    if (t < SCAN_B) bpre[t] = sd[t] - v;   // exclusive
}

// writes row_ptr AND cursor (cursor starts at row start; k_fill bumps it)
__global__ void k_scan3(const int* __restrict__ deg, const int* __restrict__ bpre,
                        int* __restrict__ row_ptr, int* __restrict__ cursor) {
    __shared__ int sd[256];
    int t = threadIdx.x; int i = blockIdx.x * 256 + t;
    int v = (i < N_NODES) ? deg[i] : 0;
    sd[t] = v; __syncthreads();
    for (int o = 1; o < 256; o <<= 1) {
        int x = sd[t] + ((t >= o) ? sd[t - o] : 0);
        __syncthreads(); sd[t] = x; __syncthreads();
    }
    if (i <= N_NODES) {
        int rp = bpre[blockIdx.x] + sd[t] - v;   // i==N gets E
        row_ptr[i] = rp;
        if (i < N_NODES) cursor[i] = rp;
    }
}

__global__ void k_fill(const int* __restrict__ src, const int* __restrict__ dst,
                       int* __restrict__ cursor, u16* __restrict__ col_src) {
    int e = blockIdx.x * 256 + threadIdx.x;
    if (e < N_EDGES) {
        int pos = atomicAdd(&cursor[dst[e]], 1);
        col_src[pos] = (u16)src[e];
    }
}

// ---------------- fp32 -> bf16 hi plane ----------------
__global__ __launch_bounds__(256) void k_split(
        const float* __restrict__ x, u16* __restrict__ xh) {
    long i4 = ((long)blockIdx.x * 256 + threadIdx.x) * 4;
    f32x4 v = *(const f32x4*)(x + i4);
    us4 h;
    #pragma unroll
    for (int j = 0; j < 4; ++j) h[j] = f2bf(v[j]);
    *(us4*)(xh + i4) = h;
}

// ---------------- aggregation: mean of source rows (bf16 in/out) ----------------
// 16 lanes per node, 16B (8 dims) per lane; 4x unrolled.
__global__ __launch_bounds__(256) void k_agg(
        const u16* __restrict__ fh,
        const int* __restrict__ row_ptr, const u16* __restrict__ col_src,
        u16* __restrict__ oh) {
    int tid = threadIdx.x;
    int grp = tid >> 4;          // 0..15
    int g   = tid & 15;
    int node = blockIdx.x * 16 + grp;    // grid 3125 -> exactly 50000
    int s = row_ptr[node], e = row_ptr[node + 1];
    int d8 = g * 8;
    float sum[8] = {0.f, 0.f, 0.f, 0.f, 0.f, 0.f, 0.f, 0.f};
    int j = s;
    for (; j + 4 <= e; j += 4) {
        int i0 = col_src[j], i1 = col_src[j + 1], i2 = col_src[j + 2], i3 = col_src[j + 3];
        us8 h0 = *(const us8*)(fh + (long)i0 * DIM + d8);
        us8 h1 = *(const us8*)(fh + (long)i1 * DIM + d8);
        us8 h2 = *(const us8*)(fh + (long)i2 * DIM + d8);
        us8 h3 = *(const us8*)(fh + (long)i3 * DIM + d8);
        #pragma unroll
        for (int k = 0; k < 8; ++k)
            sum[k] += (bf2f(h0[k]) + bf2f(h1[k])) + (bf2f(h2[k]) + bf2f(h3[k]));
    }
    for (; j < e; ++j) {
        int i0 = col_src[j];
        us8 h0 = *(const us8*)(fh + (long)i0 * DIM + d8);
        #pragma unroll
        for (int k = 0; k < 8; ++k) sum[k] += bf2f(h0[k]);
    }
    float dn = (e > s) ? 1.f / (float)(e - s) : 1.f;
    us8 rh;
    #pragma unroll
    for (int k = 0; k < 8; ++k) rh[k] = f2bf(sum[k] * dn);
    *(us8*)(oh + (long)node * DIM + d8) = rh;
}

// ---------------- B packing for MFMA fragment order ----------------
// Bp[((nt*8+kc)*64 + lane)*8 + j] = B[kc*32 + (lane>>4)*8 + j][nt*16 + (lane&15)]
__global__ void k_pack_b(const float* __restrict__ Wl, const float* __restrict__ Wr,
                         u16* __restrict__ Bph) {
    int idx = blockIdx.x * 256 + threadIdx.x;        // 4096 total
    if (idx >= 8 * 8 * 64) return;
    int lane = idx & 63;
    int kc = (idx >> 6) & 7;
    int nt = idx >> 9;
    int q = lane >> 4, nn = lane & 15;
    int col = nt * 16 + nn;
    #pragma unroll
    for (int j = 0; j < 8; ++j) {
        int k = kc * 32 + q * 8 + j;
        float v = (k < 128) ? Wl[k * 128 + col] : Wr[(k - 128) * 128 + col];
        Bph[(long)idx * 8 + j] = f2bf(v);
    }
}

// ---------------- fused GEMM + BN column stats, barrier-free K-loop, cg=2 ----------------
// out = [Agg | Root](N x 256) @ B(256 x 128) + bias; stats += {col sums, col sumsq}
// Wave = 16 rows x 64 cols; block = 4 waves = 64 rows x 64 cols; grid = 782 rb x 2 cg.
// A read 2x total; B 32 KB/wave from L2; no big LDS, high occupancy (~24 waves/CU).
__global__ __launch_bounds__(256) void k_gemm(
        const u16* __restrict__ AggH, const u16* __restrict__ RootH,
        const u16* __restrict__ Bph, const float* __restrict__ bias,
        float* __restrict__ outH, float* __restrict__ stats) {
    __shared__ float smem_s[64], smem_q[64];
    int tid = threadIdx.x;
    int wave = tid >> 6, lane = tid & 63;
    int q = lane >> 4, nn = lane & 15;
    int rb = blockIdx.x >> 1, cg = blockIdx.x & 1;
    int rowbase = rb * 64 + wave * 16;
    int arow = rowbase + nn;
    long rc = (arow < N_NODES) ? arow : 0;

    if (tid < 64) { smem_s[tid] = 0.f; smem_q[tid] = 0.f; }
    __syncthreads();

    f32x4 acc[4];
    #pragma unroll
    for (int i = 0; i < 4; ++i) acc[i] = (f32x4){0.f, 0.f, 0.f, 0.f};

    #pragma unroll
    for (int kc = 0; kc < 8; ++kc) {
        const u16* ph = (kc < 4) ? AggH : RootH;
        int ko = (kc & 3) * 32 + q * 8;
        short8 ah = *(const short8*)(ph + rc * DIM + ko);
        #pragma unroll
        for (int nt = 0; nt < 4; ++nt) {
            int ntg = cg * 4 + nt;
            short8 bh = *(const short8*)(Bph + (((ntg * 8 + kc) * 64 + lane) << 3));
            acc[nt] = __builtin_amdgcn_mfma_f32_16x16x32_bf16(ah, bh, acc[nt], 0, 0, 0);
        }
    }

    #pragma unroll
    for (int nt = 0; nt < 4; ++nt) {
        int col = cg * 64 + nt * 16 + nn;
        float bv = bias[col];
        float ps = 0.f, pq = 0.f;
        #pragma unroll
        for (int r = 0; r < 4; ++r) {
            int orow = rowbase + q * 4 + r;
            if (orow < N_NODES) {
                float v = acc[nt][r] + bv;
                outH[(long)orow * DIM + col] = v;
                ps += v; pq += v * v;
            }
        }
        atomicAdd(&smem_s[nt * 16 + nn], ps);
        atomicAdd(&smem_q[nt * 16 + nn], pq);
    }
    __syncthreads();
    if (tid < 64) {
        atomicAdd(&stats[cg * 64 + tid], smem_s[tid]);
        atomicAdd(&stats[128 + cg * 64 + tid], smem_q[tid]);
    }
}

// ---------------- BN apply (dense stats: sum at c, sumsq at 128+c) ----------------

// h1r = relu(bn(h)); writes bf16 hi plane (consumed by agg2 + gemm2 root)
__global__ __launch_bounds__(256) void k_bn_relu(
        const float* __restrict__ h, const float* __restrict__ stats,
        const float* __restrict__ g, const float* __restrict__ bt,
        u16* __restrict__ oh) {
    long i4 = ((long)blockIdx.x * 256 + threadIdx.x) * 4;
    int c = (int)(i4 & 127);
    f32x4 hv = *(const f32x4*)(h + i4);
    f32x4 s0 = *(const f32x4*)(stats + c);
    f32x4 s1 = *(const f32x4*)(stats + 128 + c);
    f32x4 gv = *(const f32x4*)(g + c);
    f32x4 bv = *(const f32x4*)(bt + c);
    us4 rh;
    #pragma unroll
    for (int j = 0; j < 4; ++j) {
        float mu = s0[j] * NINV;
        float var = s1[j] * NINV - mu * mu;
        float a = gv[j] * rsqrtf(var + 1e-5f);
        float v = (hv[j] - mu) * a + bv[j];
        v = v > 0.f ? v : 0.f;
        rh[j] = f2bf(v);
    }
    *(us4*)(oh + i4) = rh;
}

// out = relu(bn(h) + x), fp32
__global__ __launch_bounds__(256) void k_bn_add_relu(
        const float* __restrict__ h, const float* __restrict__ stats,
        const float* __restrict__ g, const float* __restrict__ bt,
        const float* __restrict__ x, float* __restrict__ outv) {
    long i4 = ((long)blockIdx.x * 256 + threadIdx.x) * 4;
    int c = (int)(i4 & 127);
    f32x4 hv = *(const f32x4*)(h + i4);
    f32x4 xv = *(const f32x4*)(x + i4);
    f32x4 s0 = *(const f32x4*)(stats + c);
    f32x4 s1 = *(const f32x4*)(stats + 128 + c);
    f32x4 gv = *(const f32x4*)(g + c);
    f32x4 bv = *(const f32x4*)(bt + c);
    f32x4 r;
    #pragma unroll
    for (int j = 0; j < 4; ++j) {
        float mu = s0[j] * NINV;
        float var = s1[j] * NINV - mu * mu;
        float a = gv[j] * rsqrtf(var + 1e-5f);
        float v = (hv[j] - mu) * a + bv[j] + xv[j];
        r[j] = v > 0.f ? v : 0.f;
    }
    *(f32x4*)(outv + i4) = r;
}

extern "C" void kernel_launch(void* const* d_in, const int* in_sizes, int n_in,
                              void* d_out, int out_size, void* d_ws, size_t ws_size,
                              hipStream_t stream) {
    (void)in_sizes; (void)n_in; (void)out_size; (void)ws_size;
    const float* x   = (const float*)d_in[0];
    const int*   ei  = (const int*)d_in[1];
    const float* W1l = (const float*)d_in[2];
    const float* b1  = (const float*)d_in[3];
    const float* W1r = (const float*)d_in[4];
    const float* g1  = (const float*)d_in[5];
    const float* bt1 = (const float*)d_in[6];
    const float* W2l = (const float*)d_in[7];
    const float* b2  = (const float*)d_in[8];
    const float* W2r = (const float*)d_in[9];
    const float* g2  = (const float*)d_in[10];
    const float* bt2 = (const float*)d_in[11];
    float* out = (float*)d_out;

    const int* esrc = ei;
    const int* edst = ei + N_EDGES;

    char* ws = (char*)d_ws;
    size_t off = 0;
    auto alloc = [&](size_t bytes) { size_t p = off; off = (off + bytes + 255) & ~(size_t)255; return p; };
    int*   deg     = (int*)  (ws + alloc(N_NODES * 4));
    float* stats1  = (float*)(ws + alloc(256 * 4));
    float* stats2  = (float*)(ws + alloc(256 * 4));
    size_t zero_bytes = off;                       // everything above must be zeroed
    int*   cursor  = (int*)  (ws + alloc(N_NODES * 4));
    int*   row_ptr = (int*)  (ws + alloc((N_NODES + 1) * 4));
    int*   bsum    = (int*)  (ws + alloc(256 * 4));
    int*   bpre    = (int*)  (ws + alloc(256 * 4));
    u16*   col_src = (u16*)  (ws + alloc((size_t)N_EDGES * 2));
    u16*   xh      = (u16*)  (ws + alloc((size_t)N_NODES * DIM * 2));  // reused as h1r hi
    u16*   aggh    = (u16*)  (ws + alloc((size_t)N_NODES * DIM * 2));
    float* hbuf    = (float*)(ws + alloc((size_t)N_NODES * DIM * 4));
    u16*   Bp1h    = (u16*)  (ws + alloc(256 * 128 * 2));
    u16*   Bp2h    = (u16*)  (ws + alloc(256 * 128 * 2));

    hipMemsetAsync(ws, 0, zero_bytes, stream);

    const int EB = (N_EDGES + 255) / 256;            // 3125
    const int GEMMB = ((N_NODES + 63) / 64) * 2;     // 782 rb x 2 cg = 1564
    const int AGGB = N_NODES / 16;                   // 3125 exact
    const int EWB4 = (int)(((long)N_NODES * DIM) / 1024);  // 6250 exact

    // weight packing + x hi-plane (independent of CSR)
    k_pack_b<<<16, 256, 0, stream>>>(W1l, W1r, Bp1h);
    k_pack_b<<<16, 256, 0, stream>>>(W2l, W2r, Bp2h);
    k_split<<<EWB4, 256, 0, stream>>>(x, xh);

    // CSR build
    k_deg_hist<<<EB, 256, 0, stream>>>(edst, deg);
    k_scan1<<<SCAN_B, 256, 0, stream>>>(deg, bsum);
    k_scan2<<<1, 256, 0, stream>>>(bsum, bpre);
    k_scan3<<<SCAN_B, 256, 0, stream>>>(deg, bpre, row_ptr, cursor);
    k_fill<<<EB, 256, 0, stream>>>(esrc, edst, cursor, col_src);

    // stage 1
    k_agg<<<AGGB, 256, 0, stream>>>(xh, row_ptr, col_src, aggh);
    k_gemm<<<GEMMB, 256, 0, stream>>>(aggh, xh, Bp1h, b1, hbuf, stats1);
    k_bn_relu<<<EWB4, 256, 0, stream>>>(hbuf, stats1, g1, bt1, xh);  // xh now holds h1r hi

    // stage 2
    k_agg<<<AGGB, 256, 0, stream>>>(xh, row_ptr, col_src, aggh);
    k_gemm<<<GEMMB, 256, 0, stream>>>(aggh, xh, Bp2h, b2, hbuf, stats2);
    k_bn_add_relu<<<EWB4, 256, 0, stream>>>(hbuf, stats2, g2, bt2, x, out);
}

// Round 11
// 305.200 us; speedup vs baseline: 2.0627x; 1.1234x over previous
//
#include <hip/hip_runtime.h>

typedef unsigned short u16;
typedef __attribute__((ext_vector_type(8))) short short8;
typedef __attribute__((ext_vector_type(4))) float f32x4;
typedef __attribute__((ext_vector_type(4))) unsigned short us4;
typedef __attribute__((ext_vector_type(8))) unsigned short us8;

#define N_NODES 50000
#define N_EDGES 800000
#define DIM 128
#define SCAN_B 196   /* ceil(50000/256) */
#define NINV (1.0f / 50000.0f)

__device__ __forceinline__ float bf2f(u16 u) {
    union { unsigned int i; float f; } v; v.i = ((unsigned int)u) << 16; return v.f;
}
__device__ __forceinline__ u16 f2bf(float f) {
    union { float f; unsigned int i; } v; v.f = f;
    return (u16)((v.i + 0x7FFFu + ((v.i >> 16) & 1u)) >> 16);
}

// ---------------- CSR build ----------------

__global__ void k_deg_hist(const int* __restrict__ dst, int* __restrict__ deg) {
    int e = blockIdx.x * 256 + threadIdx.x;
    if (e < N_EDGES) atomicAdd(&deg[dst[e]], 1);
}

__global__ void k_scan1(const int* __restrict__ deg, int* __restrict__ bsum) {
    __shared__ int sd[256];
    int t = threadIdx.x; int i = blockIdx.x * 256 + t;
    sd[t] = (i < N_NODES) ? deg[i] : 0;
    __syncthreads();
    for (int o = 128; o > 0; o >>= 1) { if (t < o) sd[t] += sd[t + o]; __syncthreads(); }
    if (t == 0) bsum[blockIdx.x] = sd[0];
}

__global__ void k_scan2(const int* __restrict__ bsum, int* __restrict__ bpre) {
    __shared__ int sd[256];
    int t = threadIdx.x;
    int v = (t < SCAN_B) ? bsum[t] : 0;
    sd[t] = v; __syncthreads();
    for (int o = 1; o < 256; o <<= 1) {
        int x = sd[t] + ((t >= o) ? sd[t - o] : 0);
        __syncthreads(); sd[t] = x; __syncthreads();
    }
    if (t < SCAN_B) bpre[t] = sd[t] - v;   // exclusive
}

// writes row_ptr AND cursor (cursor starts at row start; k_fill bumps it)
__global__ void k_scan3(const int* __restrict__ deg, const int* __restrict__ bpre,
                        int* __restrict__ row_ptr, int* __restrict__ cursor) {
    __shared__ int sd[256];
    int t = threadIdx.x; int i = blockIdx.x * 256 + t;
    int v = (i < N_NODES) ? deg[i] : 0;
    sd[t] = v; __syncthreads();
    for (int o = 1; o < 256; o <<= 1) {
        int x = sd[t] + ((t >= o) ? sd[t - o] : 0);
        __syncthreads(); sd[t] = x; __syncthreads();
    }
    if (i <= N_NODES) {
        int rp = bpre[blockIdx.x] + sd[t] - v;   // i==N gets E
        row_ptr[i] = rp;
        if (i < N_NODES) cursor[i] = rp;
    }
}

__global__ void k_fill(const int* __restrict__ src, const int* __restrict__ dst,
                       int* __restrict__ cursor, u16* __restrict__ col_src) {
    int e = blockIdx.x * 256 + threadIdx.x;
    if (e < N_EDGES) {
        int pos = atomicAdd(&cursor[dst[e]], 1);
        col_src[pos] = (u16)src[e];
    }
}

// ---------------- fp32 -> bf16 hi plane ----------------
__global__ __launch_bounds__(256) void k_split(
        const float* __restrict__ x, u16* __restrict__ xh) {
    long i4 = ((long)blockIdx.x * 256 + threadIdx.x) * 4;
    f32x4 v = *(const f32x4*)(x + i4);
    us4 h;
    #pragma unroll
    for (int j = 0; j < 4; ++j) h[j] = f2bf(v[j]);
    *(us4*)(xh + i4) = h;
}

// ---------------- aggregation: mean of source rows (bf16 in/out) ----------------
// 16 lanes per node, 16B (8 dims) per lane; 4x unrolled.
__global__ __launch_bounds__(256) void k_agg(
        const u16* __restrict__ fh,
        const int* __restrict__ row_ptr, const u16* __restrict__ col_src,
        u16* __restrict__ oh) {
    int tid = threadIdx.x;
    int grp = tid >> 4;          // 0..15
    int g   = tid & 15;
    int node = blockIdx.x * 16 + grp;    // grid 3125 -> exactly 50000
    int s = row_ptr[node], e = row_ptr[node + 1];
    int d8 = g * 8;
    float sum[8] = {0.f, 0.f, 0.f, 0.f, 0.f, 0.f, 0.f, 0.f};
    int j = s;
    for (; j + 4 <= e; j += 4) {
        int i0 = col_src[j], i1 = col_src[j + 1], i2 = col_src[j + 2], i3 = col_src[j + 3];
        us8 h0 = *(const us8*)(fh + (long)i0 * DIM + d8);
        us8 h1 = *(const us8*)(fh + (long)i1 * DIM + d8);
        us8 h2 = *(const us8*)(fh + (long)i2 * DIM + d8);
        us8 h3 = *(const us8*)(fh + (long)i3 * DIM + d8);
        #pragma unroll
        for (int k = 0; k < 8; ++k)
            sum[k] += (bf2f(h0[k]) + bf2f(h1[k])) + (bf2f(h2[k]) + bf2f(h3[k]));
    }
    for (; j < e; ++j) {
        int i0 = col_src[j];
        us8 h0 = *(const us8*)(fh + (long)i0 * DIM + d8);
        #pragma unroll
        for (int k = 0; k < 8; ++k) sum[k] += bf2f(h0[k]);
    }
    float dn = (e > s) ? 1.f / (float)(e - s) : 1.f;
    us8 rh;
    #pragma unroll
    for (int k = 0; k < 8; ++k) rh[k] = f2bf(sum[k] * dn);
    *(us8*)(oh + (long)node * DIM + d8) = rh;
}

// ---------------- B packing for MFMA fragment order ----------------
// Bp[((nt*8+kc)*64 + lane)*8 + j] = B[kc*32 + (lane>>4)*8 + j][nt*16 + (lane&15)]
__global__ void k_pack_b(const float* __restrict__ Wl, const float* __restrict__ Wr,
                         u16* __restrict__ Bph) {
    int idx = blockIdx.x * 256 + threadIdx.x;        // 4096 total
    if (idx >= 8 * 8 * 64) return;
    int lane = idx & 63;
    int kc = (idx >> 6) & 7;
    int nt = idx >> 9;
    int q = lane >> 4, nn = lane & 15;
    int col = nt * 16 + nn;
    #pragma unroll
    for (int j = 0; j < 8; ++j) {
        int k = kc * 32 + q * 8 + j;
        float v = (k < 128) ? Wl[k * 128 + col] : Wr[(k - 128) * 128 + col];
        Bph[(long)idx * 8 + j] = f2bf(v);
    }
}

// ---------------- fused GEMM + BN stats; col-split INSIDE block ----------------
// h16 = bf16([Agg|Root](N x 256) @ B(256 x 128) + bias); banked col sums/sumsq.
// Block = one 16-row tile x 128 cols; wave cg=0..3 covers cols cg*32..+31.
// Grid 3125 (max block parallelism); A frags preloaded (all loads independent);
// A shared across the 4 waves via L1. No LDS, no barriers.
__global__ __launch_bounds__(256) void k_gemm(
        const u16* __restrict__ AggH, const u16* __restrict__ RootH,
        const u16* __restrict__ Bph, const float* __restrict__ bias,
        u16* __restrict__ h16, float* __restrict__ stats) {
    int tid = threadIdx.x;
    int cg = tid >> 6, lane = tid & 63;
    int q = lane >> 4, nn = lane & 15;
    long rowbase = (long)blockIdx.x * 16;          // 3125*16 == 50000 exact
    long rc = rowbase + nn;

    short8 ah[8];
    #pragma unroll
    for (int kc = 0; kc < 4; ++kc)
        ah[kc] = *(const short8*)(AggH + rc * DIM + kc * 32 + q * 8);
    #pragma unroll
    for (int kc = 0; kc < 4; ++kc)
        ah[4 + kc] = *(const short8*)(RootH + rc * DIM + kc * 32 + q * 8);

    f32x4 acc[2];
    acc[0] = (f32x4){0.f, 0.f, 0.f, 0.f};
    acc[1] = (f32x4){0.f, 0.f, 0.f, 0.f};

    #pragma unroll
    for (int kc = 0; kc < 8; ++kc) {
        #pragma unroll
        for (int nt = 0; nt < 2; ++nt) {
            int ntg = cg * 2 + nt;
            short8 bh = *(const short8*)(Bph + (((ntg * 8 + kc) * 64 + lane) << 3));
            acc[nt] = __builtin_amdgcn_mfma_f32_16x16x32_bf16(ah[kc], bh, acc[nt], 0, 0, 0);
        }
    }

    int bank = blockIdx.x & 7;
    #pragma unroll
    for (int nt = 0; nt < 2; ++nt) {
        int col = cg * 32 + nt * 16 + nn;
        float bv = bias[col];
        float ps = 0.f, pq = 0.f;
        #pragma unroll
        for (int r = 0; r < 4; ++r) {
            float v = acc[nt][r] + bv;
            h16[(rowbase + q * 4 + r) * DIM + col] = f2bf(v);
            ps += v; pq += v * v;
        }
        ps += __shfl_xor(ps, 16);
        ps += __shfl_xor(ps, 32);
        pq += __shfl_xor(pq, 16);
        pq += __shfl_xor(pq, 32);
        if (q == 0) {
            atomicAdd(&stats[bank * 512 + col], ps);
            atomicAdd(&stats[bank * 512 + 256 + col], pq);
        }
    }
}

// ---------------- fold banked stats -> per-col scale/offset ----------------
// ac[c] = g/sqrt(var+eps); ac[128+c] = bt - mu*ac[c]
__global__ void k_bn_coeff(const float* __restrict__ stats, const float* __restrict__ g,
                           const float* __restrict__ bt, float* __restrict__ ac) {
    int c = threadIdx.x;  // 128
    float s = 0.f, qq = 0.f;
    #pragma unroll
    for (int b = 0; b < 8; ++b) {
        s += stats[b * 512 + c] + stats[b * 512 + 128 + c] * 0.f; // keep layout simple
        s += stats[b * 512 + 128 + c] * 0.f;
        qq += stats[b * 512 + 256 + c];
    }
    // NOTE: sums live at bank*512 + col (col 0..127), sumsq at bank*512 + 256 + col.
    float mu = s * NINV;
    float var = qq * NINV - mu * mu;
    float a = g[c] * rsqrtf(var + 1e-5f);
    ac[c] = a;
    ac[128 + c] = bt[c] - mu * a;
}

// ---------------- BN apply ----------------

// h1r = relu(h*a + b); bf16 in, bf16 out; 8 elems/thread, grid 3125
__global__ __launch_bounds__(256) void k_bn_relu(
        const u16* __restrict__ h, const float* __restrict__ ac,
        u16* __restrict__ oh) {
    long i8 = ((long)blockIdx.x * 256 + threadIdx.x) * 8;
    int c = (int)(i8 & 127);
    us8 hv = *(const us8*)(h + i8);
    f32x4 a0 = *(const f32x4*)(ac + c);
    f32x4 a1 = *(const f32x4*)(ac + c + 4);
    f32x4 o0 = *(const f32x4*)(ac + 128 + c);
    f32x4 o1 = *(const f32x4*)(ac + 128 + c + 4);
    us8 rh;
    #pragma unroll
    for (int j = 0; j < 4; ++j) {
        float v = bf2f(hv[j]) * a0[j] + o0[j];
        rh[j] = f2bf(v > 0.f ? v : 0.f);
        float w = bf2f(hv[4 + j]) * a1[j] + o1[j];
        rh[4 + j] = f2bf(w > 0.f ? w : 0.f);
    }
    *(us8*)(oh + i8) = rh;
}

// out = relu(h*a + b + x), fp32 out; 8 elems/thread, grid 3125
__global__ __launch_bounds__(256) void k_bn_add_relu(
        const u16* __restrict__ h, const float* __restrict__ ac,
        const float* __restrict__ x, float* __restrict__ outv) {
    long i8 = ((long)blockIdx.x * 256 + threadIdx.x) * 8;
    int c = (int)(i8 & 127);
    us8 hv = *(const us8*)(h + i8);
    f32x4 x0 = *(const f32x4*)(x + i8);
    f32x4 x1 = *(const f32x4*)(x + i8 + 4);
    f32x4 a0 = *(const f32x4*)(ac + c);
    f32x4 a1 = *(const f32x4*)(ac + c + 4);
    f32x4 o0 = *(const f32x4*)(ac + 128 + c);
    f32x4 o1 = *(const f32x4*)(ac + 128 + c + 4);
    f32x4 r0, r1;
    #pragma unroll
    for (int j = 0; j < 4; ++j) {
        float v = bf2f(hv[j]) * a0[j] + o0[j] + x0[j];
        r0[j] = v > 0.f ? v : 0.f;
        float w = bf2f(hv[4 + j]) * a1[j] + o1[j] + x1[j];
        r1[j] = w > 0.f ? w : 0.f;
    }
    *(f32x4*)(outv + i8) = r0;
    *(f32x4*)(outv + i8 + 4) = r1;
}

extern "C" void kernel_launch(void* const* d_in, const int* in_sizes, int n_in,
                              void* d_out, int out_size, void* d_ws, size_t ws_size,
                              hipStream_t stream) {
    (void)in_sizes; (void)n_in; (void)out_size; (void)ws_size;
    const float* x   = (const float*)d_in[0];
    const int*   ei  = (const int*)d_in[1];
    const float* W1l = (const float*)d_in[2];
    const float* b1  = (const float*)d_in[3];
    const float* W1r = (const float*)d_in[4];
    const float* g1  = (const float*)d_in[5];
    const float* bt1 = (const float*)d_in[6];
    const float* W2l = (const float*)d_in[7];
    const float* b2  = (const float*)d_in[8];
    const float* W2r = (const float*)d_in[9];
    const float* g2  = (const float*)d_in[10];
    const float* bt2 = (const float*)d_in[11];
    float* out = (float*)d_out;

    const int* esrc = ei;
    const int* edst = ei + N_EDGES;

    char* ws = (char*)d_ws;
    size_t off = 0;
    auto alloc = [&](size_t bytes) { size_t p = off; off = (off + bytes + 255) & ~(size_t)255; return p; };
    int*   deg     = (int*)  (ws + alloc(N_NODES * 4));
    float* stats1  = (float*)(ws + alloc(4096 * 4));   // 8 banks x 512 (sum@+col, sumsq@+256+col)
    float* stats2  = (float*)(ws + alloc(4096 * 4));
    size_t zero_bytes = off;                       // everything above must be zeroed
    float* ac1     = (float*)(ws + alloc(256 * 4));
    float* ac2     = (float*)(ws + alloc(256 * 4));
    int*   cursor  = (int*)  (ws + alloc(N_NODES * 4));
    int*   row_ptr = (int*)  (ws + alloc((N_NODES + 1) * 4));
    int*   bsum    = (int*)  (ws + alloc(256 * 4));
    int*   bpre    = (int*)  (ws + alloc(256 * 4));
    u16*   col_src = (u16*)  (ws + alloc((size_t)N_EDGES * 2));
    u16*   xh      = (u16*)  (ws + alloc((size_t)N_NODES * DIM * 2));  // reused as h1r
    u16*   aggh    = (u16*)  (ws + alloc((size_t)N_NODES * DIM * 2));
    u16*   hb16    = (u16*)  (ws + alloc((size_t)N_NODES * DIM * 2));
    u16*   Bp1h    = (u16*)  (ws + alloc(256 * 128 * 2));
    u16*   Bp2h    = (u16*)  (ws + alloc(256 * 128 * 2));

    hipMemsetAsync(ws, 0, zero_bytes, stream);

    const int EB = (N_EDGES + 255) / 256;            // 3125
    const int GEMMB = N_NODES / 16;                  // 3125 exact
    const int AGGB = N_NODES / 16;                   // 3125 exact
    const int EWB4 = (int)(((long)N_NODES * DIM) / 1024);  // 6250 exact
    const int EWB8 = (int)(((long)N_NODES * DIM) / 2048);  // 3125 exact

    // weight packing + x hi-plane (independent of CSR)
    k_pack_b<<<16, 256, 0, stream>>>(W1l, W1r, Bp1h);
    k_pack_b<<<16, 256, 0, stream>>>(W2l, W2r, Bp2h);
    k_split<<<EWB4, 256, 0, stream>>>(x, xh);

    // CSR build
    k_deg_hist<<<EB, 256, 0, stream>>>(edst, deg);
    k_scan1<<<SCAN_B, 256, 0, stream>>>(deg, bsum);
    k_scan2<<<1, 256, 0, stream>>>(bsum, bpre);
    k_scan3<<<SCAN_B, 256, 0, stream>>>(deg, bpre, row_ptr, cursor);
    k_fill<<<EB, 256, 0, stream>>>(esrc, edst, cursor, col_src);

    // stage 1
    k_agg<<<AGGB, 256, 0, stream>>>(xh, row_ptr, col_src, aggh);
    k_gemm<<<GEMMB, 256, 0, stream>>>(aggh, xh, Bp1h, b1, hb16, stats1);
    k_bn_coeff<<<1, 128, 0, stream>>>(stats1, g1, bt1, ac1);
    k_bn_relu<<<EWB8, 256, 0, stream>>>(hb16, ac1, xh);   // xh now holds h1r

    // stage 2
    k_agg<<<AGGB, 256, 0, stream>>>(xh, row_ptr, col_src, aggh);
    k_gemm<<<GEMMB, 256, 0, stream>>>(aggh, xh, Bp2h, b2, hb16, stats2);
    k_bn_coeff<<<1, 128, 0, stream>>>(stats2, g2, bt2, ac2);
    k_bn_add_relu<<<EWB8, 256, 0, stream>>>(hb16, ac2, x, out);
}

// Round 12
// 301.904 us; speedup vs baseline: 2.0853x; 1.0109x over previous
//
#include <hip/hip_runtime.h>

typedef unsigned short u16;
typedef __attribute__((ext_vector_type(8))) short short8;
typedef __attribute__((ext_vector_type(4))) float f32x4;
typedef __attribute__((ext_vector_type(4))) unsigned short us4;
typedef __attribute__((ext_vector_type(8))) unsigned short us8;

#define N_NODES 50000
#define N_EDGES 800000
#define DIM 128
#define SCAN_B 196   /* ceil(50000/256) */
#define NINV (1.0f / 50000.0f)
#define NPART 8
#define PART_SZ 6250  /* 50000/8 */

__device__ __forceinline__ float bf2f(u16 u) {
    union { unsigned int i; float f; } v; v.i = ((unsigned int)u) << 16; return v.f;
}
__device__ __forceinline__ u16 f2bf(float f) {
    union { float f; unsigned int i; } v; v.f = f;
    return (u16)((v.i + 0x7FFFu + ((v.i >> 16) & 1u)) >> 16);
}

// ---------------- CSR build ----------------

__global__ void k_deg_hist(const int* __restrict__ dst, int* __restrict__ deg) {
    int e = blockIdx.x * 256 + threadIdx.x;
    if (e < N_EDGES) atomicAdd(&deg[dst[e]], 1);
}

__global__ void k_scan1(const int* __restrict__ deg, int* __restrict__ bsum) {
    __shared__ int sd[256];
    int t = threadIdx.x; int i = blockIdx.x * 256 + t;
    sd[t] = (i < N_NODES) ? deg[i] : 0;
    __syncthreads();
    for (int o = 128; o > 0; o >>= 1) { if (t < o) sd[t] += sd[t + o]; __syncthreads(); }
    if (t == 0) bsum[blockIdx.x] = sd[0];
}

__global__ void k_scan2(const int* __restrict__ bsum, int* __restrict__ bpre) {
    __shared__ int sd[256];
    int t = threadIdx.x;
    int v = (t < SCAN_B) ? bsum[t] : 0;
    sd[t] = v; __syncthreads();
    for (int o = 1; o < 256; o <<= 1) {
        int x = sd[t] + ((t >= o) ? sd[t - o] : 0);
        __syncthreads(); sd[t] = x; __syncthreads();
    }
    if (t < SCAN_B) bpre[t] = sd[t] - v;   // exclusive
}

// writes row_ptr AND cursor (cursor starts at row start; k_fill bumps it)
__global__ void k_scan3(const int* __restrict__ deg, const int* __restrict__ bpre,
                        int* __restrict__ row_ptr, int* __restrict__ cursor) {
    __shared__ int sd[256];
    int t = threadIdx.x; int i = blockIdx.x * 256 + t;
    int v = (i < N_NODES) ? deg[i] : 0;
    sd[t] = v; __syncthreads();
    for (int o = 1; o < 256; o <<= 1) {
        int x = sd[t] + ((t >= o) ? sd[t - o] : 0);
        __syncthreads(); sd[t] = x; __syncthreads();
    }
    if (i <= N_NODES) {
        int rp = bpre[blockIdx.x] + sd[t] - v;   // i==N gets E
        row_ptr[i] = rp;
        if (i < N_NODES) cursor[i] = rp;
    }
}

// XCD-partitioned fill: block b -> part = b&7 (matches blockIdx%8 XCD round-robin),
// chunk = b>>3. Each part writes a disjoint contiguous col_src segment -> lines
// dirtied by one XCD only, evicted once (kills the 25x write amplification).
__global__ __launch_bounds__(256) void k_fill(
        const int* __restrict__ src, const int* __restrict__ dst,
        int* __restrict__ cursor, u16* __restrict__ col_src) {
    int part = blockIdx.x & 7;
    int e = (blockIdx.x >> 3) * 256 + threadIdx.x;
    if (e < N_EDGES) {
        int d = dst[e];
        if ((unsigned)(d - part * PART_SZ) < (unsigned)PART_SZ) {
            int pos = atomicAdd(&cursor[d], 1);
            col_src[pos] = (u16)src[e];
        }
    }
}

// ---------------- fp32 -> bf16 hi plane ----------------
__global__ __launch_bounds__(256) void k_split(
        const float* __restrict__ x, u16* __restrict__ xh) {
    long i4 = ((long)blockIdx.x * 256 + threadIdx.x) * 4;
    f32x4 v = *(const f32x4*)(x + i4);
    us4 h;
    #pragma unroll
    for (int j = 0; j < 4; ++j) h[j] = f2bf(v[j]);
    *(us4*)(xh + i4) = h;
}

// ---------------- aggregation: mean of source rows (bf16 in/out) ----------------
// 16 lanes per node, 16B (8 dims) per lane; 4x unrolled.
__global__ __launch_bounds__(256) void k_agg(
        const u16* __restrict__ fh,
        const int* __restrict__ row_ptr, const u16* __restrict__ col_src,
        u16* __restrict__ oh) {
    int tid = threadIdx.x;
    int grp = tid >> 4;          // 0..15
    int g   = tid & 15;
    int node = blockIdx.x * 16 + grp;    // grid 3125 -> exactly 50000
    int s = row_ptr[node], e = row_ptr[node + 1];
    int d8 = g * 8;
    float sum[8] = {0.f, 0.f, 0.f, 0.f, 0.f, 0.f, 0.f, 0.f};
    int j = s;
    for (; j + 4 <= e; j += 4) {
        int i0 = col_src[j], i1 = col_src[j + 1], i2 = col_src[j + 2], i3 = col_src[j + 3];
        us8 h0 = *(const us8*)(fh + (long)i0 * DIM + d8);
        us8 h1 = *(const us8*)(fh + (long)i1 * DIM + d8);
        us8 h2 = *(const us8*)(fh + (long)i2 * DIM + d8);
        us8 h3 = *(const us8*)(fh + (long)i3 * DIM + d8);
        #pragma unroll
        for (int k = 0; k < 8; ++k)
            sum[k] += (bf2f(h0[k]) + bf2f(h1[k])) + (bf2f(h2[k]) + bf2f(h3[k]));
    }
    for (; j < e; ++j) {
        int i0 = col_src[j];
        us8 h0 = *(const us8*)(fh + (long)i0 * DIM + d8);
        #pragma unroll
        for (int k = 0; k < 8; ++k) sum[k] += bf2f(h0[k]);
    }
    float dn = (e > s) ? 1.f / (float)(e - s) : 1.f;
    us8 rh;
    #pragma unroll
    for (int k = 0; k < 8; ++k) rh[k] = f2bf(sum[k] * dn);
    *(us8*)(oh + (long)node * DIM + d8) = rh;
}

// ---------------- B packing for MFMA fragment order ----------------
// Bp[((nt*8+kc)*64 + lane)*8 + j] = B[kc*32 + (lane>>4)*8 + j][nt*16 + (lane&15)]
__global__ void k_pack_b(const float* __restrict__ Wl, const float* __restrict__ Wr,
                         u16* __restrict__ Bph) {
    int idx = blockIdx.x * 256 + threadIdx.x;        // 4096 total
    if (idx >= 8 * 8 * 64) return;
    int lane = idx & 63;
    int kc = (idx >> 6) & 7;
    int nt = idx >> 9;
    int q = lane >> 4, nn = lane & 15;
    int col = nt * 16 + nn;
    #pragma unroll
    for (int j = 0; j < 8; ++j) {
        int k = kc * 32 + q * 8 + j;
        float v = (k < 128) ? Wl[k * 128 + col] : Wr[(k - 128) * 128 + col];
        Bph[(long)idx * 8 + j] = f2bf(v);
    }
}

// ---------------- fused GEMM + BN stats; col-split INSIDE block ----------------
// h16 = bf16([Agg|Root](N x 256) @ B(256 x 128) + bias); banked col sums/sumsq.
// Block = one 16-row tile x 128 cols; wave cg=0..3 covers cols cg*32..+31.
// Grid 3125; A frags preloaded (all loads independent); A shared across waves via L1.
__global__ __launch_bounds__(256) void k_gemm(
        const u16* __restrict__ AggH, const u16* __restrict__ RootH,
        const u16* __restrict__ Bph, const float* __restrict__ bias,
        u16* __restrict__ h16, float* __restrict__ stats) {
    int tid = threadIdx.x;
    int cg = tid >> 6, lane = tid & 63;
    int q = lane >> 4, nn = lane & 15;
    long rowbase = (long)blockIdx.x * 16;          // 3125*16 == 50000 exact
    long rc = rowbase + nn;

    short8 ah[8];
    #pragma unroll
    for (int kc = 0; kc < 4; ++kc)
        ah[kc] = *(const short8*)(AggH + rc * DIM + kc * 32 + q * 8);
    #pragma unroll
    for (int kc = 0; kc < 4; ++kc)
        ah[4 + kc] = *(const short8*)(RootH + rc * DIM + kc * 32 + q * 8);

    f32x4 acc[2];
    acc[0] = (f32x4){0.f, 0.f, 0.f, 0.f};
    acc[1] = (f32x4){0.f, 0.f, 0.f, 0.f};

    #pragma unroll
    for (int kc = 0; kc < 8; ++kc) {
        #pragma unroll
        for (int nt = 0; nt < 2; ++nt) {
            int ntg = cg * 2 + nt;
            short8 bh = *(const short8*)(Bph + (((ntg * 8 + kc) * 64 + lane) << 3));
            acc[nt] = __builtin_amdgcn_mfma_f32_16x16x32_bf16(ah[kc], bh, acc[nt], 0, 0, 0);
        }
    }

    int bank = blockIdx.x & 7;
    #pragma unroll
    for (int nt = 0; nt < 2; ++nt) {
        int col = cg * 32 + nt * 16 + nn;
        float bv = bias[col];
        float ps = 0.f, pq = 0.f;
        #pragma unroll
        for (int r = 0; r < 4; ++r) {
            float v = acc[nt][r] + bv;
            h16[(rowbase + q * 4 + r) * DIM + col] = f2bf(v);
            ps += v; pq += v * v;
        }
        ps += __shfl_xor(ps, 16);
        ps += __shfl_xor(ps, 32);
        pq += __shfl_xor(pq, 16);
        pq += __shfl_xor(pq, 32);
        if (q == 0) {
            atomicAdd(&stats[bank * 512 + col], ps);
            atomicAdd(&stats[bank * 512 + 256 + col], pq);
        }
    }
}

// ---------------- fold banked stats -> per-col scale/offset ----------------
// ac[c] = g/sqrt(var+eps); ac[128+c] = bt - mu*ac[c]
__global__ void k_bn_coeff(const float* __restrict__ stats, const float* __restrict__ g,
                           const float* __restrict__ bt, float* __restrict__ ac) {
    int c = threadIdx.x;  // 128
    float s = 0.f, qq = 0.f;
    #pragma unroll
    for (int b = 0; b < 8; ++b) {
        s  += stats[b * 512 + c];
        qq += stats[b * 512 + 256 + c];
    }
    float mu = s * NINV;
    float var = qq * NINV - mu * mu;
    float a = g[c] * rsqrtf(var + 1e-5f);
    ac[c] = a;
    ac[128 + c] = bt[c] - mu * a;
}

// ---------------- BN apply ----------------

// h1r = relu(h*a + b); bf16 in, bf16 out; 8 elems/thread, grid 3125
__global__ __launch_bounds__(256) void k_bn_relu(
        const u16* __restrict__ h, const float* __restrict__ ac,
        u16* __restrict__ oh) {
    long i8 = ((long)blockIdx.x * 256 + threadIdx.x) * 8;
    int c = (int)(i8 & 127);
    us8 hv = *(const us8*)(h + i8);
    f32x4 a0 = *(const f32x4*)(ac + c);
    f32x4 a1 = *(const f32x4*)(ac + c + 4);
    f32x4 o0 = *(const f32x4*)(ac + 128 + c);
    f32x4 o1 = *(const f32x4*)(ac + 128 + c + 4);
    us8 rh;
    #pragma unroll
    for (int j = 0; j < 4; ++j) {
        float v = bf2f(hv[j]) * a0[j] + o0[j];
        rh[j] = f2bf(v > 0.f ? v : 0.f);
        float w = bf2f(hv[4 + j]) * a1[j] + o1[j];
        rh[4 + j] = f2bf(w > 0.f ? w : 0.f);
    }
    *(us8*)(oh + i8) = rh;
}

// out = relu(h*a + b + x), fp32 out; 8 elems/thread, grid 3125
__global__ __launch_bounds__(256) void k_bn_add_relu(
        const u16* __restrict__ h, const float* __restrict__ ac,
        const float* __restrict__ x, float* __restrict__ outv) {
    long i8 = ((long)blockIdx.x * 256 + threadIdx.x) * 8;
    int c = (int)(i8 & 127);
    us8 hv = *(const us8*)(h + i8);
    f32x4 x0 = *(const f32x4*)(x + i8);
    f32x4 x1 = *(const f32x4*)(x + i8 + 4);
    f32x4 a0 = *(const f32x4*)(ac + c);
    f32x4 a1 = *(const f32x4*)(ac + c + 4);
    f32x4 o0 = *(const f32x4*)(ac + 128 + c);
    f32x4 o1 = *(const f32x4*)(ac + 128 + c + 4);
    f32x4 r0, r1;
    #pragma unroll
    for (int j = 0; j < 4; ++j) {
        float v = bf2f(hv[j]) * a0[j] + o0[j] + x0[j];
        r0[j] = v > 0.f ? v : 0.f;
        float w = bf2f(hv[4 + j]) * a1[j] + o1[j] + x1[j];
        r1[j] = w > 0.f ? w : 0.f;
    }
    *(f32x4*)(outv + i8) = r0;
    *(f32x4*)(outv + i8 + 4) = r1;
}

extern "C" void kernel_launch(void* const* d_in, const int* in_sizes, int n_in,
                              void* d_out, int out_size, void* d_ws, size_t ws_size,
                              hipStream_t stream) {
    (void)in_sizes; (void)n_in; (void)out_size; (void)ws_size;
    const float* x   = (const float*)d_in[0];
    const int*   ei  = (const int*)d_in[1];
    const float* W1l = (const float*)d_in[2];
    const float* b1  = (const float*)d_in[3];
    const float* W1r = (const float*)d_in[4];
    const float* g1  = (const float*)d_in[5];
    const float* bt1 = (const float*)d_in[6];
    const float* W2l = (const float*)d_in[7];
    const float* b2  = (const float*)d_in[8];
    const float* W2r = (const float*)d_in[9];
    const float* g2  = (const float*)d_in[10];
    const float* bt2 = (const float*)d_in[11];
    float* out = (float*)d_out;

    const int* esrc = ei;
    const int* edst = ei + N_EDGES;

    char* ws = (char*)d_ws;
    size_t off = 0;
    auto alloc = [&](size_t bytes) { size_t p = off; off = (off + bytes + 255) & ~(size_t)255; return p; };
    int*   deg     = (int*)  (ws + alloc(N_NODES * 4));
    float* stats1  = (float*)(ws + alloc(4096 * 4));   // 8 banks x 512 (sum@+col, sumsq@+256+col)
    float* stats2  = (float*)(ws + alloc(4096 * 4));
    size_t zero_bytes = off;                       // everything above must be zeroed
    float* ac1     = (float*)(ws + alloc(256 * 4));
    float* ac2     = (float*)(ws + alloc(256 * 4));
    int*   cursor  = (int*)  (ws + alloc(N_NODES * 4));
    int*   row_ptr = (int*)  (ws + alloc((N_NODES + 1) * 4));
    int*   bsum    = (int*)  (ws + alloc(256 * 4));
    int*   bpre    = (int*)  (ws + alloc(256 * 4));
    u16*   col_src = (u16*)  (ws + alloc((size_t)N_EDGES * 2));
    u16*   xh      = (u16*)  (ws + alloc((size_t)N_NODES * DIM * 2));  // reused as h1r
    u16*   aggh    = (u16*)  (ws + alloc((size_t)N_NODES * DIM * 2));
    u16*   hb16    = (u16*)  (ws + alloc((size_t)N_NODES * DIM * 2));
    u16*   Bp1h    = (u16*)  (ws + alloc(256 * 128 * 2));
    u16*   Bp2h    = (u16*)  (ws + alloc(256 * 128 * 2));

    hipMemsetAsync(ws, 0, zero_bytes, stream);

    const int EB = (N_EDGES + 255) / 256;            // 3125
    const int FILLB = EB * NPART;                    // 25000 (8 partition passes)
    const int GEMMB = N_NODES / 16;                  // 3125 exact
    const int AGGB = N_NODES / 16;                   // 3125 exact
    const int EWB4 = (int)(((long)N_NODES * DIM) / 1024);  // 6250 exact
    const int EWB8 = (int)(((long)N_NODES * DIM) / 2048);  // 3125 exact

    // weight packing + x hi-plane (independent of CSR)
    k_pack_b<<<16, 256, 0, stream>>>(W1l, W1r, Bp1h);
    k_pack_b<<<16, 256, 0, stream>>>(W2l, W2r, Bp2h);
    k_split<<<EWB4, 256, 0, stream>>>(x, xh);

    // CSR build
    k_deg_hist<<<EB, 256, 0, stream>>>(edst, deg);
    k_scan1<<<SCAN_B, 256, 0, stream>>>(deg, bsum);
    k_scan2<<<1, 256, 0, stream>>>(bsum, bpre);
    k_scan3<<<SCAN_B, 256, 0, stream>>>(deg, bpre, row_ptr, cursor);
    k_fill<<<FILLB, 256, 0, stream>>>(esrc, edst, cursor, col_src);

    // stage 1
    k_agg<<<AGGB, 256, 0, stream>>>(xh, row_ptr, col_src, aggh);
    k_gemm<<<GEMMB, 256, 0, stream>>>(aggh, xh, Bp1h, b1, hb16, stats1);
    k_bn_coeff<<<1, 128, 0, stream>>>(stats1, g1, bt1, ac1);
    k_bn_relu<<<EWB8, 256, 0, stream>>>(hb16, ac1, xh);   // xh now holds h1r

    // stage 2
    k_agg<<<AGGB, 256, 0, stream>>>(xh, row_ptr, col_src, aggh);
    k_gemm<<<GEMMB, 256, 0, stream>>>(aggh, xh, Bp2h, b2, hb16, stats2);
    k_bn_coeff<<<1, 128, 0, stream>>>(stats2, g2, bt2, ac2);
    k_bn_add_relu<<<EWB8, 256, 0, stream>>>(hb16, ac2, x, out);
}

// Round 13
// 286.038 us; speedup vs baseline: 2.2009x; 1.0555x over previous
//
#include <hip/hip_runtime.h>

typedef unsigned short u16;
typedef __attribute__((ext_vector_type(8))) short short8;
typedef __attribute__((ext_vector_type(4))) float f32x4;
typedef __attribute__((ext_vector_type(4))) unsigned short us4;
typedef __attribute__((ext_vector_type(8))) unsigned short us8;

#define N_NODES 50000
#define N_EDGES 800000
#define DIM 128
#define SCAN_B 196   /* ceil(50000/256) */
#define NINV (1.0f / 50000.0f)
#define NPART 8
#define PART_SZ 6250  /* 50000/8 */
#define SROW 136      /* LDS row stride (u16) — pad keeps ds conflicts <=2-way */

__device__ __forceinline__ float bf2f(u16 u) {
    union { unsigned int i; float f; } v; v.i = ((unsigned int)u) << 16; return v.f;
}
__device__ __forceinline__ u16 f2bf(float f) {
    union { float f; unsigned int i; } v; v.f = f;
    return (u16)((v.i + 0x7FFFu + ((v.i >> 16) & 1u)) >> 16);
}

// ---------------- CSR build ----------------

__global__ void k_deg_hist(const int* __restrict__ dst, int* __restrict__ deg) {
    int e = blockIdx.x * 256 + threadIdx.x;
    if (e < N_EDGES) atomicAdd(&deg[dst[e]], 1);
}

__global__ void k_scan1(const int* __restrict__ deg, int* __restrict__ bsum) {
    __shared__ int sd[256];
    int t = threadIdx.x; int i = blockIdx.x * 256 + t;
    sd[t] = (i < N_NODES) ? deg[i] : 0;
    __syncthreads();
    for (int o = 128; o > 0; o >>= 1) { if (t < o) sd[t] += sd[t + o]; __syncthreads(); }
    if (t == 0) bsum[blockIdx.x] = sd[0];
}

__global__ void k_scan2(const int* __restrict__ bsum, int* __restrict__ bpre) {
    __shared__ int sd[256];
    int t = threadIdx.x;
    int v = (t < SCAN_B) ? bsum[t] : 0;
    sd[t] = v; __syncthreads();
    for (int o = 1; o < 256; o <<= 1) {
        int x = sd[t] + ((t >= o) ? sd[t - o] : 0);
        __syncthreads(); sd[t] = x; __syncthreads();
    }
    if (t < SCAN_B) bpre[t] = sd[t] - v;   // exclusive
}

// writes row_ptr AND cursor (cursor starts at row start; k_fill bumps it)
__global__ void k_scan3(const int* __restrict__ deg, const int* __restrict__ bpre,
                        int* __restrict__ row_ptr, int* __restrict__ cursor) {
    __shared__ int sd[256];
    int t = threadIdx.x; int i = blockIdx.x * 256 + t;
    int v = (i < N_NODES) ? deg[i] : 0;
    sd[t] = v; __syncthreads();
    for (int o = 1; o < 256; o <<= 1) {
        int x = sd[t] + ((t >= o) ? sd[t - o] : 0);
        __syncthreads(); sd[t] = x; __syncthreads();
    }
    if (i <= N_NODES) {
        int rp = bpre[blockIdx.x] + sd[t] - v;   // i==N gets E
        row_ptr[i] = rp;
        if (i < N_NODES) cursor[i] = rp;
    }
}

// XCD-partitioned fill: block b -> part = b&7 (matches blockIdx%8 XCD round-robin),
// chunk = b>>3. Each part writes a disjoint contiguous col_src segment.
__global__ __launch_bounds__(256) void k_fill(
        const int* __restrict__ src, const int* __restrict__ dst,
        int* __restrict__ cursor, u16* __restrict__ col_src) {
    int part = blockIdx.x & 7;
    int e = (blockIdx.x >> 3) * 256 + threadIdx.x;
    if (e < N_EDGES) {
        int d = dst[e];
        if ((unsigned)(d - part * PART_SZ) < (unsigned)PART_SZ) {
            int pos = atomicAdd(&cursor[d], 1);
            col_src[pos] = (u16)src[e];
        }
    }
}

// ---------------- fp32 -> bf16 hi plane ----------------
__global__ __launch_bounds__(256) void k_split(
        const float* __restrict__ x, u16* __restrict__ xh) {
    long i4 = ((long)blockIdx.x * 256 + threadIdx.x) * 4;
    f32x4 v = *(const f32x4*)(x + i4);
    us4 h;
    #pragma unroll
    for (int j = 0; j < 4; ++j) h[j] = f2bf(v[j]);
    *(us4*)(xh + i4) = h;
}

// ---------------- B packing for MFMA fragment order ----------------
// Bp[((nt*8+kc)*64 + lane)*8 + j] = B[kc*32 + (lane>>4)*8 + j][nt*16 + (lane&15)]
__global__ void k_pack_b(const float* __restrict__ Wl, const float* __restrict__ Wr,
                         u16* __restrict__ Bph) {
    int idx = blockIdx.x * 256 + threadIdx.x;        // 4096 total
    if (idx >= 8 * 8 * 64) return;
    int lane = idx & 63;
    int kc = (idx >> 6) & 7;
    int nt = idx >> 9;
    int q = lane >> 4, nn = lane & 15;
    int col = nt * 16 + nn;
    #pragma unroll
    for (int j = 0; j < 8; ++j) {
        int k = kc * 32 + q * 8 + j;
        float v = (k < 128) ? Wl[k * 128 + col] : Wr[(k - 128) * 128 + col];
        Bph[(long)idx * 8 + j] = f2bf(v);
    }
}

// ---------------- fused AGG + GEMM + BN stats ----------------
// Block = one 16-row M-tile, 256 thr, grid 3125.
// Phase 1: gather-mean 16 nodes x 128 dims -> LDS (BN: relu(a*v+b) per element first).
// Phase 2: MFMA [Agg|Root] @ B; root frags from global (BN transform at preload).
// Epilogue: h16 = bf16(acc + bias); banked col sums/sumsq.
template<int BN>
__global__ __launch_bounds__(256) void k_ag(
        const u16* __restrict__ fh,
        const int* __restrict__ row_ptr, const u16* __restrict__ col_src,
        const u16* __restrict__ Bph, const float* __restrict__ bias,
        const float* __restrict__ ac,
        u16* __restrict__ h16, float* __restrict__ stats) {
    __shared__ u16 sA[16 * SROW];
    int tid = threadIdx.x;
    long nodebase = (long)blockIdx.x * 16;       // 3125*16 == 50000 exact

    // ---- phase 1: gather-mean ----
    {
        int grp = tid >> 4, g = tid & 15;
        int node = (int)nodebase + grp;
        int s = row_ptr[node], e = row_ptr[node + 1];
        int d8 = g * 8;
        float av[8], ov[8];
        if (BN) {
            #pragma unroll
            for (int k = 0; k < 8; ++k) { av[k] = ac[d8 + k]; ov[k] = ac[128 + d8 + k]; }
        }
        float sum[8] = {0.f, 0.f, 0.f, 0.f, 0.f, 0.f, 0.f, 0.f};
        int j = s;
        for (; j + 4 <= e; j += 4) {
            int i0 = col_src[j], i1 = col_src[j + 1], i2 = col_src[j + 2], i3 = col_src[j + 3];
            us8 h0 = *(const us8*)(fh + (long)i0 * DIM + d8);
            us8 h1 = *(const us8*)(fh + (long)i1 * DIM + d8);
            us8 h2 = *(const us8*)(fh + (long)i2 * DIM + d8);
            us8 h3 = *(const us8*)(fh + (long)i3 * DIM + d8);
            #pragma unroll
            for (int k = 0; k < 8; ++k) {
                if (BN) {
                    float v0 = bf2f(h0[k]) * av[k] + ov[k]; v0 = v0 > 0.f ? v0 : 0.f;
                    float v1 = bf2f(h1[k]) * av[k] + ov[k]; v1 = v1 > 0.f ? v1 : 0.f;
                    float v2 = bf2f(h2[k]) * av[k] + ov[k]; v2 = v2 > 0.f ? v2 : 0.f;
                    float v3 = bf2f(h3[k]) * av[k] + ov[k]; v3 = v3 > 0.f ? v3 : 0.f;
                    sum[k] += (v0 + v1) + (v2 + v3);
                } else {
                    sum[k] += (bf2f(h0[k]) + bf2f(h1[k])) + (bf2f(h2[k]) + bf2f(h3[k]));
                }
            }
        }
        for (; j < e; ++j) {
            int i0 = col_src[j];
            us8 h0 = *(const us8*)(fh + (long)i0 * DIM + d8);
            #pragma unroll
            for (int k = 0; k < 8; ++k) {
                if (BN) {
                    float v0 = bf2f(h0[k]) * av[k] + ov[k];
                    sum[k] += v0 > 0.f ? v0 : 0.f;
                } else {
                    sum[k] += bf2f(h0[k]);
                }
            }
        }
        float dn = (e > s) ? 1.f / (float)(e - s) : 1.f;
        us8 rh;
        #pragma unroll
        for (int k = 0; k < 8; ++k) rh[k] = f2bf(sum[k] * dn);
        *(us8*)(sA + grp * SROW + d8) = rh;
    }
    __syncthreads();

    // ---- phase 2: MFMA ----
    int cg = tid >> 6, lane = tid & 63;
    int q = lane >> 4, nn = lane & 15;
    long rc = nodebase + nn;

    short8 ah[8];
    #pragma unroll
    for (int kc = 0; kc < 4; ++kc)
        ah[kc] = *(const short8*)(sA + nn * SROW + kc * 32 + q * 8);
    #pragma unroll
    for (int kc = 0; kc < 4; ++kc) {
        int ko = kc * 32 + q * 8;
        us8 rv = *(const us8*)(fh + rc * DIM + ko);
        short8 t;
        if (BN) {
            #pragma unroll
            for (int j = 0; j < 8; ++j) {
                float v = bf2f(rv[j]) * ac[ko + j] + ac[128 + ko + j];
                t[j] = (short)f2bf(v > 0.f ? v : 0.f);
            }
        } else {
            #pragma unroll
            for (int j = 0; j < 8; ++j) t[j] = (short)rv[j];
        }
        ah[4 + kc] = t;
    }

    f32x4 acc[2];
    acc[0] = (f32x4){0.f, 0.f, 0.f, 0.f};
    acc[1] = (f32x4){0.f, 0.f, 0.f, 0.f};

    #pragma unroll
    for (int kc = 0; kc < 8; ++kc) {
        #pragma unroll
        for (int nt = 0; nt < 2; ++nt) {
            int ntg = cg * 2 + nt;
            short8 bh = *(const short8*)(Bph + (((ntg * 8 + kc) * 64 + lane) << 3));
            acc[nt] = __builtin_amdgcn_mfma_f32_16x16x32_bf16(ah[kc], bh, acc[nt], 0, 0, 0);
        }
    }

    int bank = blockIdx.x & 7;
    #pragma unroll
    for (int nt = 0; nt < 2; ++nt) {
        int col = cg * 32 + nt * 16 + nn;
        float bv = bias[col];
        float ps = 0.f, pq = 0.f;
        #pragma unroll
        for (int r = 0; r < 4; ++r) {
            float v = acc[nt][r] + bv;
            h16[(nodebase + q * 4 + r) * DIM + col] = f2bf(v);
            ps += v; pq += v * v;
        }
        ps += __shfl_xor(ps, 16);
        ps += __shfl_xor(ps, 32);
        pq += __shfl_xor(pq, 16);
        pq += __shfl_xor(pq, 32);
        if (q == 0) {
            atomicAdd(&stats[bank * 512 + col], ps);
            atomicAdd(&stats[bank * 512 + 256 + col], pq);
        }
    }
}

// ---------------- fold banked stats -> per-col scale/offset ----------------
// ac[c] = g/sqrt(var+eps); ac[128+c] = bt - mu*ac[c]
__global__ void k_bn_coeff(const float* __restrict__ stats, const float* __restrict__ g,
                           const float* __restrict__ bt, float* __restrict__ ac) {
    int c = threadIdx.x;  // 128
    float s = 0.f, qq = 0.f;
    #pragma unroll
    for (int b = 0; b < 8; ++b) {
        s  += stats[b * 512 + c];
        qq += stats[b * 512 + 256 + c];
    }
    float mu = s * NINV;
    float var = qq * NINV - mu * mu;
    float a = g[c] * rsqrtf(var + 1e-5f);
    ac[c] = a;
    ac[128 + c] = bt[c] - mu * a;
}

// out = relu(h*a + b + x), fp32 out; 8 elems/thread, grid 3125
__global__ __launch_bounds__(256) void k_bn_add_relu(
        const u16* __restrict__ h, const float* __restrict__ ac,
        const float* __restrict__ x, float* __restrict__ outv) {
    long i8 = ((long)blockIdx.x * 256 + threadIdx.x) * 8;
    int c = (int)(i8 & 127);
    us8 hv = *(const us8*)(h + i8);
    f32x4 x0 = *(const f32x4*)(x + i8);
    f32x4 x1 = *(const f32x4*)(x + i8 + 4);
    f32x4 a0 = *(const f32x4*)(ac + c);
    f32x4 a1 = *(const f32x4*)(ac + c + 4);
    f32x4 o0 = *(const f32x4*)(ac + 128 + c);
    f32x4 o1 = *(const f32x4*)(ac + 128 + c + 4);
    f32x4 r0, r1;
    #pragma unroll
    for (int j = 0; j < 4; ++j) {
        float v = bf2f(hv[j]) * a0[j] + o0[j] + x0[j];
        r0[j] = v > 0.f ? v : 0.f;
        float w = bf2f(hv[4 + j]) * a1[j] + o1[j] + x1[j];
        r1[j] = w > 0.f ? w : 0.f;
    }
    *(f32x4*)(outv + i8) = r0;
    *(f32x4*)(outv + i8 + 4) = r1;
}

extern "C" void kernel_launch(void* const* d_in, const int* in_sizes, int n_in,
                              void* d_out, int out_size, void* d_ws, size_t ws_size,
                              hipStream_t stream) {
    (void)in_sizes; (void)n_in; (void)out_size; (void)ws_size;
    const float* x   = (const float*)d_in[0];
    const int*   ei  = (const int*)d_in[1];
    const float* W1l = (const float*)d_in[2];
    const float* b1  = (const float*)d_in[3];
    const float* W1r = (const float*)d_in[4];
    const float* g1  = (const float*)d_in[5];
    const float* bt1 = (const float*)d_in[6];
    const float* W2l = (const float*)d_in[7];
    const float* b2  = (const float*)d_in[8];
    const float* W2r = (const float*)d_in[9];
    const float* g2  = (const float*)d_in[10];
    const float* bt2 = (const float*)d_in[11];
    float* out = (float*)d_out;

    const int* esrc = ei;
    const int* edst = ei + N_EDGES;

    char* ws = (char*)d_ws;
    size_t off = 0;
    auto alloc = [&](size_t bytes) { size_t p = off; off = (off + bytes + 255) & ~(size_t)255; return p; };
    int*   deg     = (int*)  (ws + alloc(N_NODES * 4));
    float* stats1  = (float*)(ws + alloc(4096 * 4));   // 8 banks x 512 (sum@+col, sumsq@+256+col)
    float* stats2  = (float*)(ws + alloc(4096 * 4));
    size_t zero_bytes = off;                       // everything above must be zeroed
    float* ac1     = (float*)(ws + alloc(256 * 4));
    float* ac2     = (float*)(ws + alloc(256 * 4));
    int*   cursor  = (int*)  (ws + alloc(N_NODES * 4));
    int*   row_ptr = (int*)  (ws + alloc((N_NODES + 1) * 4));
    int*   bsum    = (int*)  (ws + alloc(256 * 4));
    int*   bpre    = (int*)  (ws + alloc(256 * 4));
    u16*   col_src = (u16*)  (ws + alloc((size_t)N_EDGES * 2));
    u16*   xh      = (u16*)  (ws + alloc((size_t)N_NODES * DIM * 2));
    u16*   hb1     = (u16*)  (ws + alloc((size_t)N_NODES * DIM * 2));  // raw h1 (pre-BN)
    u16*   hb2     = (u16*)  (ws + alloc((size_t)N_NODES * DIM * 2));  // raw h2 (pre-BN)
    u16*   Bp1h    = (u16*)  (ws + alloc(256 * 128 * 2));
    u16*   Bp2h    = (u16*)  (ws + alloc(256 * 128 * 2));

    hipMemsetAsync(ws, 0, zero_bytes, stream);

    const int EB = (N_EDGES + 255) / 256;            // 3125
    const int FILLB = EB * NPART;                    // 25000 (8 partition passes)
    const int AGB = N_NODES / 16;                    // 3125 exact
    const int EWB4 = (int)(((long)N_NODES * DIM) / 1024);  // 6250 exact
    const int EWB8 = (int)(((long)N_NODES * DIM) / 2048);  // 3125 exact

    // weight packing + x hi-plane (independent of CSR)
    k_pack_b<<<16, 256, 0, stream>>>(W1l, W1r, Bp1h);
    k_pack_b<<<16, 256, 0, stream>>>(W2l, W2r, Bp2h);
    k_split<<<EWB4, 256, 0, stream>>>(x, xh);

    // CSR build
    k_deg_hist<<<EB, 256, 0, stream>>>(edst, deg);
    k_scan1<<<SCAN_B, 256, 0, stream>>>(deg, bsum);
    k_scan2<<<1, 256, 0, stream>>>(bsum, bpre);
    k_scan3<<<SCAN_B, 256, 0, stream>>>(deg, bpre, row_ptr, cursor);
    k_fill<<<FILLB, 256, 0, stream>>>(esrc, edst, cursor, col_src);

    // stage 1: fused agg+gemm on x
    k_ag<0><<<AGB, 256, 0, stream>>>(xh, row_ptr, col_src, Bp1h, b1, ac1, hb1, stats1);
    k_bn_coeff<<<1, 128, 0, stream>>>(stats1, g1, bt1, ac1);

    // stage 2: fused agg+gemm on h1 with BN+relu applied at operand load
    k_ag<1><<<AGB, 256, 0, stream>>>(hb1, row_ptr, col_src, Bp2h, b2, ac1, hb2, stats2);
    k_bn_coeff<<<1, 128, 0, stream>>>(stats2, g2, bt2, ac2);

    // epilogue: out = relu(bn(h2) + x)
    k_bn_add_relu<<<EWB8, 256, 0, stream>>>(hb2, ac2, x, out);
}

// Round 14
// 271.181 us; speedup vs baseline: 2.3215x; 1.0548x over previous
//
#include <hip/hip_runtime.h>

typedef unsigned short u16;
typedef unsigned char u8;
typedef __attribute__((ext_vector_type(8))) short short8;
typedef __attribute__((ext_vector_type(2))) float f32x2;
typedef __attribute__((ext_vector_type(4))) float f32x4;
typedef __attribute__((ext_vector_type(4))) unsigned short us4;
typedef __attribute__((ext_vector_type(8))) unsigned short us8;
typedef __attribute__((ext_vector_type(2))) unsigned int u32x2;

#define N_NODES 50000
#define N_EDGES 800000
#define DIM 128
#define SCAN_B 196   /* ceil(50000/256) */
#define NINV (1.0f / 50000.0f)
#define NPART 8
#define PART_SZ 6250  /* 50000/8 */
#define SROW 136      /* LDS row stride (u16) */

__device__ __forceinline__ float bf2f(u16 u) {
    union { unsigned int i; float f; } v; v.i = ((unsigned int)u) << 16; return v.f;
}
__device__ __forceinline__ u16 f2bf(float f) {
    union { float f; unsigned int i; } v; v.f = f;
    return (u16)((v.i + 0x7FFFu + ((v.i >> 16) & 1u)) >> 16);
}

// ---------------- CSR build ----------------

__global__ void k_deg_hist(const int* __restrict__ dst, int* __restrict__ deg) {
    int e = blockIdx.x * 256 + threadIdx.x;
    if (e < N_EDGES) atomicAdd(&deg[dst[e]], 1);
}

__global__ void k_scan1(const int* __restrict__ deg, int* __restrict__ bsum) {
    __shared__ int sd[256];
    int t = threadIdx.x; int i = blockIdx.x * 256 + t;
    sd[t] = (i < N_NODES) ? deg[i] : 0;
    __syncthreads();
    for (int o = 128; o > 0; o >>= 1) { if (t < o) sd[t] += sd[t + o]; __syncthreads(); }
    if (t == 0) bsum[blockIdx.x] = sd[0];
}

__global__ void k_scan2(const int* __restrict__ bsum, int* __restrict__ bpre) {
    __shared__ int sd[256];
    int t = threadIdx.x;
    int v = (t < SCAN_B) ? bsum[t] : 0;
    sd[t] = v; __syncthreads();
    for (int o = 1; o < 256; o <<= 1) {
        int x = sd[t] + ((t >= o) ? sd[t - o] : 0);
        __syncthreads(); sd[t] = x; __syncthreads();
    }
    if (t < SCAN_B) bpre[t] = sd[t] - v;   // exclusive
}

__global__ void k_scan3(const int* __restrict__ deg, const int* __restrict__ bpre,
                        int* __restrict__ row_ptr, int* __restrict__ cursor) {
    __shared__ int sd[256];
    int t = threadIdx.x; int i = blockIdx.x * 256 + t;
    int v = (i < N_NODES) ? deg[i] : 0;
    sd[t] = v; __syncthreads();
    for (int o = 1; o < 256; o <<= 1) {
        int x = sd[t] + ((t >= o) ? sd[t - o] : 0);
        __syncthreads(); sd[t] = x; __syncthreads();
    }
    if (i <= N_NODES) {
        int rp = bpre[blockIdx.x] + sd[t] - v;   // i==N gets E
        row_ptr[i] = rp;
        if (i < N_NODES) cursor[i] = rp;
    }
}

// XCD-partitioned fill (see R12): part = blockIdx&7, chunk = blockIdx>>3.
__global__ __launch_bounds__(256) void k_fill(
        const int* __restrict__ src, const int* __restrict__ dst,
        int* __restrict__ cursor, u16* __restrict__ col_src) {
    int part = blockIdx.x & 7;
    int e = (blockIdx.x >> 3) * 256 + threadIdx.x;
    if (e < N_EDGES) {
        int d = dst[e];
        if ((unsigned)(d - part * PART_SZ) < (unsigned)PART_SZ) {
            int pos = atomicAdd(&cursor[d], 1);
            col_src[pos] = (u16)src[e];
        }
    }
}

// ---------------- prep: pack B1, pack B2, split x -> bf16 + fp8 planes ----------------
// blocks 0..15: pack B1; 16..31: pack B2; 32..6281: split x.
__global__ __launch_bounds__(256) void k_prep(
        const float* __restrict__ W1l, const float* __restrict__ W1r, u16* __restrict__ Bp1,
        const float* __restrict__ W2l, const float* __restrict__ W2r, u16* __restrict__ Bp2,
        const float* __restrict__ x, u16* __restrict__ xh, u8* __restrict__ xf8) {
    int b = blockIdx.x;
    if (b < 32) {
        const float* Wl = (b < 16) ? W1l : W2l;
        const float* Wr = (b < 16) ? W1r : W2r;
        u16* Bp = (b < 16) ? Bp1 : Bp2;
        int idx = (b & 15) * 256 + threadIdx.x;      // 0..4095
        int lane = idx & 63;
        int kc = (idx >> 6) & 7;
        int nt = idx >> 9;
        int q = lane >> 4, nn = lane & 15;
        int col = nt * 16 + nn;
        #pragma unroll
        for (int j = 0; j < 8; ++j) {
            int k = kc * 32 + q * 8 + j;
            float v = (k < 128) ? Wl[k * 128 + col] : Wr[(k - 128) * 128 + col];
            Bp[(long)idx * 8 + j] = f2bf(v);
        }
    } else {
        long i4 = ((long)(b - 32) * 256 + threadIdx.x) * 4;
        f32x4 v = *(const f32x4*)(x + i4);
        us4 h;
        #pragma unroll
        for (int j = 0; j < 4; ++j) h[j] = f2bf(v[j]);
        *(us4*)(xh + i4) = h;
        int p = __builtin_amdgcn_cvt_pk_fp8_f32(v[0], v[1], 0, false);
        p = __builtin_amdgcn_cvt_pk_fp8_f32(v[2], v[3], p, true);
        *(int*)(xf8 + i4) = p;
    }
}

// decode 8 fp8 + (optional BN+relu) + accumulate
template<int BN>
__device__ __forceinline__ void acc_row(unsigned int w0, unsigned int w1,
        float sum[8], const float av[8], const float ov[8]) {
    float t[8];
    f32x2 p;
    p = __builtin_amdgcn_cvt_pk_f32_fp8((int)w0, false); t[0] = p[0]; t[1] = p[1];
    p = __builtin_amdgcn_cvt_pk_f32_fp8((int)w0, true);  t[2] = p[0]; t[3] = p[1];
    p = __builtin_amdgcn_cvt_pk_f32_fp8((int)w1, false); t[4] = p[0]; t[5] = p[1];
    p = __builtin_amdgcn_cvt_pk_f32_fp8((int)w1, true);  t[6] = p[0]; t[7] = p[1];
    #pragma unroll
    for (int k = 0; k < 8; ++k) {
        float v = t[k];
        if (BN) { v = v * av[k] + ov[k]; v = v > 0.f ? v : 0.f; }
        sum[k] += v;
    }
}

// ---------------- fused AGG + GEMM + BN stats ----------------
// fq: fp8 gather plane; fh: bf16 root plane (same logical tensor).
// BN: apply relu(a*v+o) to operands (coeffs computed in-block from prev stats).
// W8: also emit fp8 plane of the output (for next stage's gather).
template<int BN, int W8>
__global__ __launch_bounds__(256) void k_ag(
        const u8* __restrict__ fq, const u16* __restrict__ fh,
        const int* __restrict__ row_ptr, const u16* __restrict__ col_src,
        const u16* __restrict__ Bph, const float* __restrict__ bias,
        const float* __restrict__ statsPrev, const float* __restrict__ gP,
        const float* __restrict__ btP,
        u16* __restrict__ h16, u8* __restrict__ h8, float* __restrict__ stats) {
    __shared__ u16 sA[16 * SROW];
    __shared__ float acS[256];
    int tid = threadIdx.x;
    long nodebase = (long)blockIdx.x * 16;       // 3125*16 == 50000 exact

    if (BN) {
        if (tid < 128) {
            float s = 0.f, qq = 0.f;
            #pragma unroll
            for (int b = 0; b < 8; ++b) {
                s  += statsPrev[b * 512 + tid];
                qq += statsPrev[b * 512 + 256 + tid];
            }
            float mu = s * NINV;
            float var = qq * NINV - mu * mu;
            float a = gP[tid] * rsqrtf(var + 1e-5f);
            acS[tid] = a;
            acS[128 + tid] = btP[tid] - mu * a;
        }
        __syncthreads();
    }

    // ---- phase 1: gather-mean (fp8 operand) ----
    {
        int grp = tid >> 4, g = tid & 15;
        int node = (int)nodebase + grp;
        int s = row_ptr[node], e = row_ptr[node + 1];
        int d8 = g * 8;
        float av[8], ov[8];
        if (BN) {
            #pragma unroll
            for (int k = 0; k < 8; ++k) { av[k] = acS[d8 + k]; ov[k] = acS[128 + d8 + k]; }
        }
        float sum[8] = {0.f, 0.f, 0.f, 0.f, 0.f, 0.f, 0.f, 0.f};
        int j = s;
        for (; j + 4 <= e; j += 4) {
            int i0 = col_src[j], i1 = col_src[j + 1], i2 = col_src[j + 2], i3 = col_src[j + 3];
            u32x2 w0 = *(const u32x2*)(fq + (long)i0 * DIM + d8);
            u32x2 w1 = *(const u32x2*)(fq + (long)i1 * DIM + d8);
            u32x2 w2 = *(const u32x2*)(fq + (long)i2 * DIM + d8);
            u32x2 w3 = *(const u32x2*)(fq + (long)i3 * DIM + d8);
            acc_row<BN>(w0[0], w0[1], sum, av, ov);
            acc_row<BN>(w1[0], w1[1], sum, av, ov);
            acc_row<BN>(w2[0], w2[1], sum, av, ov);
            acc_row<BN>(w3[0], w3[1], sum, av, ov);
        }
        for (; j < e; ++j) {
            int i0 = col_src[j];
            u32x2 w0 = *(const u32x2*)(fq + (long)i0 * DIM + d8);
            acc_row<BN>(w0[0], w0[1], sum, av, ov);
        }
        float dn = (e > s) ? 1.f / (float)(e - s) : 1.f;
        us8 rh;
        #pragma unroll
        for (int k = 0; k < 8; ++k) rh[k] = f2bf(sum[k] * dn);
        *(us8*)(sA + grp * SROW + d8) = rh;
    }
    __syncthreads();

    // ---- phase 2: MFMA ----
    int cg = tid >> 6, lane = tid & 63;
    int q = lane >> 4, nn = lane & 15;
    long rc = nodebase + nn;

    short8 ah[8];
    #pragma unroll
    for (int kc = 0; kc < 4; ++kc)
        ah[kc] = *(const short8*)(sA + nn * SROW + kc * 32 + q * 8);
    #pragma unroll
    for (int kc = 0; kc < 4; ++kc) {
        int ko = kc * 32 + q * 8;
        us8 rv = *(const us8*)(fh + rc * DIM + ko);
        short8 t;
        if (BN) {
            #pragma unroll
            for (int j = 0; j < 8; ++j) {
                float v = bf2f(rv[j]) * acS[ko + j] + acS[128 + ko + j];
                t[j] = (short)f2bf(v > 0.f ? v : 0.f);
            }
        } else {
            #pragma unroll
            for (int j = 0; j < 8; ++j) t[j] = (short)rv[j];
        }
        ah[4 + kc] = t;
    }

    f32x4 acc[2];
    acc[0] = (f32x4){0.f, 0.f, 0.f, 0.f};
    acc[1] = (f32x4){0.f, 0.f, 0.f, 0.f};

    #pragma unroll
    for (int kc = 0; kc < 8; ++kc) {
        #pragma unroll
        for (int nt = 0; nt < 2; ++nt) {
            int ntg = cg * 2 + nt;
            short8 bh = *(const short8*)(Bph + (((ntg * 8 + kc) * 64 + lane) << 3));
            acc[nt] = __builtin_amdgcn_mfma_f32_16x16x32_bf16(ah[kc], bh, acc[nt], 0, 0, 0);
        }
    }

    int bank = blockIdx.x & 7;
    #pragma unroll
    for (int nt = 0; nt < 2; ++nt) {
        int col = cg * 32 + nt * 16 + nn;
        float bv = bias[col];
        float ps = 0.f, pq = 0.f;
        #pragma unroll
        for (int r = 0; r < 4; ++r) {
            float v = acc[nt][r] + bv;
            long idx = (nodebase + q * 4 + r) * DIM + col;
            h16[idx] = f2bf(v);
            if (W8) {
                int pb = __builtin_amdgcn_cvt_pk_fp8_f32(v, v, 0, false);
                h8[idx] = (u8)(pb & 0xff);
            }
            ps += v; pq += v * v;
        }
        ps += __shfl_xor(ps, 16);
        ps += __shfl_xor(ps, 32);
        pq += __shfl_xor(pq, 16);
        pq += __shfl_xor(pq, 32);
        if (q == 0) {
            atomicAdd(&stats[bank * 512 + col], ps);
            atomicAdd(&stats[bank * 512 + 256 + col], pq);
        }
    }
}

// out = relu(bn(h)+x); coeffs computed in-block from banked stats
__global__ __launch_bounds__(256) void k_bn_add_relu(
        const u16* __restrict__ h, const float* __restrict__ stats,
        const float* __restrict__ g, const float* __restrict__ bt,
        const float* __restrict__ x, float* __restrict__ outv) {
    __shared__ float acS[256];
    int tid = threadIdx.x;
    if (tid < 128) {
        float s = 0.f, qq = 0.f;
        #pragma unroll
        for (int b = 0; b < 8; ++b) {
            s  += stats[b * 512 + tid];
            qq += stats[b * 512 + 256 + tid];
        }
        float mu = s * NINV;
        float var = qq * NINV - mu * mu;
        float a = g[tid] * rsqrtf(var + 1e-5f);
        acS[tid] = a;
        acS[128 + tid] = bt[tid] - mu * a;
    }
    __syncthreads();
    long i8 = ((long)blockIdx.x * 256 + tid) * 8;
    int c = (int)(i8 & 127);
    us8 hv = *(const us8*)(h + i8);
    f32x4 x0 = *(const f32x4*)(x + i8);
    f32x4 x1 = *(const f32x4*)(x + i8 + 4);
    f32x4 r0, r1;
    #pragma unroll
    for (int j = 0; j < 4; ++j) {
        float v = bf2f(hv[j]) * acS[c + j] + acS[128 + c + j] + x0[j];
        r0[j] = v > 0.f ? v : 0.f;
        float w = bf2f(hv[4 + j]) * acS[c + 4 + j] + acS[128 + c + 4 + j] + x1[j];
        r1[j] = w > 0.f ? w : 0.f;
    }
    *(f32x4*)(outv + i8) = r0;
    *(f32x4*)(outv + i8 + 4) = r1;
}

extern "C" void kernel_launch(void* const* d_in, const int* in_sizes, int n_in,
                              void* d_out, int out_size, void* d_ws, size_t ws_size,
                              hipStream_t stream) {
    (void)in_sizes; (void)n_in; (void)out_size; (void)ws_size;
    const float* x   = (const float*)d_in[0];
    const int*   ei  = (const int*)d_in[1];
    const float* W1l = (const float*)d_in[2];
    const float* b1  = (const float*)d_in[3];
    const float* W1r = (const float*)d_in[4];
    const float* g1  = (const float*)d_in[5];
    const float* bt1 = (const float*)d_in[6];
    const float* W2l = (const float*)d_in[7];
    const float* b2  = (const float*)d_in[8];
    const float* W2r = (const float*)d_in[9];
    const float* g2  = (const float*)d_in[10];
    const float* bt2 = (const float*)d_in[11];
    float* out = (float*)d_out;

    const int* esrc = ei;
    const int* edst = ei + N_EDGES;

    char* ws = (char*)d_ws;
    size_t off = 0;
    auto alloc = [&](size_t bytes) { size_t p = off; off = (off + bytes + 255) & ~(size_t)255; return p; };
    int*   deg     = (int*)  (ws + alloc(N_NODES * 4));
    float* stats1  = (float*)(ws + alloc(4096 * 4));   // 8 banks x 512 (sum@+col, sumsq@+256+col)
    float* stats2  = (float*)(ws + alloc(4096 * 4));
    size_t zero_bytes = off;                       // everything above must be zeroed
    int*   cursor  = (int*)  (ws + alloc(N_NODES * 4));
    int*   row_ptr = (int*)  (ws + alloc((N_NODES + 1) * 4));
    int*   bsum    = (int*)  (ws + alloc(256 * 4));
    int*   bpre    = (int*)  (ws + alloc(256 * 4));
    u16*   col_src = (u16*)  (ws + alloc((size_t)N_EDGES * 2));
    u16*   xh      = (u16*)  (ws + alloc((size_t)N_NODES * DIM * 2));
    u8*    xf8     = (u8*)   (ws + alloc((size_t)N_NODES * DIM));
    u16*   hb1     = (u16*)  (ws + alloc((size_t)N_NODES * DIM * 2));  // raw h1 bf16
    u8*    h1f8    = (u8*)   (ws + alloc((size_t)N_NODES * DIM));     // raw h1 fp8
    u16*   hb2     = (u16*)  (ws + alloc((size_t)N_NODES * DIM * 2));  // raw h2 bf16
    u16*   Bp1h    = (u16*)  (ws + alloc(256 * 128 * 2));
    u16*   Bp2h    = (u16*)  (ws + alloc(256 * 128 * 2));

    hipMemsetAsync(ws, 0, zero_bytes, stream);

    const int EB = (N_EDGES + 255) / 256;            // 3125
    const int FILLB = EB * NPART;                    // 25000
    const int AGB = N_NODES / 16;                    // 3125 exact
    const int EWB4 = (int)(((long)N_NODES * DIM) / 1024);  // 6250 exact
    const int EWB8 = (int)(((long)N_NODES * DIM) / 2048);  // 3125 exact
    const int PREPB = 32 + EWB4;                     // 6282

    // prep: pack both B + split x (bf16 + fp8)
    k_prep<<<PREPB, 256, 0, stream>>>(W1l, W1r, Bp1h, W2l, W2r, Bp2h, x, xh, xf8);

    // CSR build
    k_deg_hist<<<EB, 256, 0, stream>>>(edst, deg);
    k_scan1<<<SCAN_B, 256, 0, stream>>>(deg, bsum);
    k_scan2<<<1, 256, 0, stream>>>(bsum, bpre);
    k_scan3<<<SCAN_B, 256, 0, stream>>>(deg, bpre, row_ptr, cursor);
    k_fill<<<FILLB, 256, 0, stream>>>(esrc, edst, cursor, col_src);

    // stage 1: fused agg+gemm on x (fp8 gather, bf16 root); writes h1 bf16 + fp8
    k_ag<0, 1><<<AGB, 256, 0, stream>>>(xf8, xh, row_ptr, col_src, Bp1h, b1,
                                        stats1, g1, bt1, hb1, h1f8, stats1);

    // stage 2: fused agg+gemm on h1 with BN+relu at operand load (coeffs from stats1)
    k_ag<1, 0><<<AGB, 256, 0, stream>>>(h1f8, hb1, row_ptr, col_src, Bp2h, b2,
                                        stats1, g1, bt1, hb2, h1f8, stats2);

    // epilogue: out = relu(bn(h2) + x), coeffs from stats2
    k_bn_add_relu<<<EWB8, 256, 0, stream>>>(hb2, stats2, g2, bt2, x, out);
}

// Round 15
// 264.530 us; speedup vs baseline: 2.3799x; 1.0251x over previous
//
#include <hip/hip_runtime.h>

typedef unsigned short u16;
typedef unsigned char u8;
typedef __attribute__((ext_vector_type(8))) short short8;
typedef __attribute__((ext_vector_type(2))) float f32x2;
typedef __attribute__((ext_vector_type(4))) float f32x4;
typedef __attribute__((ext_vector_type(4))) unsigned short us4;
typedef __attribute__((ext_vector_type(8))) unsigned short us8;
typedef __attribute__((ext_vector_type(2))) unsigned int u32x2;
typedef __attribute__((ext_vector_type(4))) unsigned int u32x4;

#define N_NODES 50000
#define N_EDGES 800000
#define DIM 128
#define SCAN_B 196   /* ceil(50000/256) */
#define NINV (1.0f / 50000.0f)
#define NPART 8
#define PART_SZ 6250  /* 50000/8 */
#define SROW 136      /* LDS row stride (u16) */

__device__ __forceinline__ float bf2f(u16 u) {
    union { unsigned int i; float f; } v; v.i = ((unsigned int)u) << 16; return v.f;
}
__device__ __forceinline__ u16 f2bf(float f) {
    union { float f; unsigned int i; } v; v.f = f;
    return (u16)((v.i + 0x7FFFu + ((v.i >> 16) & 1u)) >> 16);
}

// ---------------- CSR scans ----------------

__global__ void k_scan1(const int* __restrict__ deg, int* __restrict__ bsum) {
    __shared__ int sd[256];
    int t = threadIdx.x; int i = blockIdx.x * 256 + t;
    sd[t] = (i < N_NODES) ? deg[i] : 0;
    __syncthreads();
    for (int o = 128; o > 0; o >>= 1) { if (t < o) sd[t] += sd[t + o]; __syncthreads(); }
    if (t == 0) bsum[blockIdx.x] = sd[0];
}

__global__ void k_scan2(const int* __restrict__ bsum, int* __restrict__ bpre) {
    __shared__ int sd[256];
    int t = threadIdx.x;
    int v = (t < SCAN_B) ? bsum[t] : 0;
    sd[t] = v; __syncthreads();
    for (int o = 1; o < 256; o <<= 1) {
        int x = sd[t] + ((t >= o) ? sd[t - o] : 0);
        __syncthreads(); sd[t] = x; __syncthreads();
    }
    if (t < SCAN_B) bpre[t] = sd[t] - v;   // exclusive
}

__global__ void k_scan3(const int* __restrict__ deg, const int* __restrict__ bpre,
                        int* __restrict__ row_ptr, int* __restrict__ cursor) {
    __shared__ int sd[256];
    int t = threadIdx.x; int i = blockIdx.x * 256 + t;
    int v = (i < N_NODES) ? deg[i] : 0;
    sd[t] = v; __syncthreads();
    for (int o = 1; o < 256; o <<= 1) {
        int x = sd[t] + ((t >= o) ? sd[t - o] : 0);
        __syncthreads(); sd[t] = x; __syncthreads();
    }
    if (i <= N_NODES) {
        int rp = bpre[blockIdx.x] + sd[t] - v;   // i==N gets E
        row_ptr[i] = rp;
        if (i < N_NODES) cursor[i] = rp;
    }
}

// XCD-partitioned fill (see R12): part = blockIdx&7, chunk = blockIdx>>3.
__global__ __launch_bounds__(256) void k_fill(
        const int* __restrict__ src, const int* __restrict__ dst,
        int* __restrict__ cursor, u16* __restrict__ col_src) {
    int part = blockIdx.x & 7;
    int e = (blockIdx.x >> 3) * 256 + threadIdx.x;
    if (e < N_EDGES) {
        int d = dst[e];
        if ((unsigned)(d - part * PART_SZ) < (unsigned)PART_SZ) {
            int pos = atomicAdd(&cursor[d], 1);
            col_src[pos] = (u16)src[e];
        }
    }
}

// ---------------- prep: pack B1/B2, split x -> bf16+fp8, degree histogram ----------------
// blocks 0..15: pack B1; 16..31: pack B2; 32..32+EWB4-1: split x; rest: deg hist.
__global__ __launch_bounds__(256) void k_prep(
        const float* __restrict__ W1l, const float* __restrict__ W1r, u16* __restrict__ Bp1,
        const float* __restrict__ W2l, const float* __restrict__ W2r, u16* __restrict__ Bp2,
        const float* __restrict__ x, u16* __restrict__ xh, u8* __restrict__ xf8,
        const int* __restrict__ edst, int* __restrict__ deg, int splitB) {
    int b = blockIdx.x;
    if (b < 32) {
        const float* Wl = (b < 16) ? W1l : W2l;
        const float* Wr = (b < 16) ? W1r : W2r;
        u16* Bp = (b < 16) ? Bp1 : Bp2;
        int idx = (b & 15) * 256 + threadIdx.x;      // 0..4095
        int lane = idx & 63;
        int kc = (idx >> 6) & 7;
        int nt = idx >> 9;
        int q = lane >> 4, nn = lane & 15;
        int col = nt * 16 + nn;
        #pragma unroll
        for (int j = 0; j < 8; ++j) {
            int k = kc * 32 + q * 8 + j;
            float v = (k < 128) ? Wl[k * 128 + col] : Wr[(k - 128) * 128 + col];
            Bp[(long)idx * 8 + j] = f2bf(v);
        }
    } else if (b < 32 + splitB) {
        long i4 = ((long)(b - 32) * 256 + threadIdx.x) * 4;
        f32x4 v = *(const f32x4*)(x + i4);
        us4 h;
        #pragma unroll
        for (int j = 0; j < 4; ++j) h[j] = f2bf(v[j]);
        *(us4*)(xh + i4) = h;
        int p = __builtin_amdgcn_cvt_pk_fp8_f32(v[0], v[1], 0, false);
        p = __builtin_amdgcn_cvt_pk_fp8_f32(v[2], v[3], p, true);
        *(int*)(xf8 + i4) = p;
    } else {
        int e = (b - 32 - splitB) * 256 + threadIdx.x;
        if (e < N_EDGES) atomicAdd(&deg[edst[e]], 1);
    }
}

// decode 16 fp8 + (optional BN+relu) + accumulate
template<int BN>
__device__ __forceinline__ void acc_row16(u32x4 w,
        float sum[16], const float av[16], const float ov[16]) {
    float t[16];
    f32x2 p;
    #pragma unroll
    for (int h = 0; h < 4; ++h) {
        p = __builtin_amdgcn_cvt_pk_f32_fp8((int)w[h], false); t[h*4+0] = p[0]; t[h*4+1] = p[1];
        p = __builtin_amdgcn_cvt_pk_f32_fp8((int)w[h], true);  t[h*4+2] = p[0]; t[h*4+3] = p[1];
    }
    #pragma unroll
    for (int k = 0; k < 16; ++k) {
        float v = t[k];
        if (BN) { v = v * av[k] + ov[k]; v = v > 0.f ? v : 0.f; }
        sum[k] += v;
    }
}

// ---------------- fused AGG + GEMM + BN stats ----------------
// Phase 1: per node, two 8-lane sub-groups process even/odd edges with 16B fp8 loads
// (full row per sub-group), combine via shfl_xor(8). Phase 2: MFMA as R13/R14.
template<int BN, int W8>
__global__ __launch_bounds__(256) void k_ag(
        const u8* __restrict__ fq, const u16* __restrict__ fh,
        const int* __restrict__ row_ptr, const u16* __restrict__ col_src,
        const u16* __restrict__ Bph, const float* __restrict__ bias,
        const float* __restrict__ statsPrev, const float* __restrict__ gP,
        const float* __restrict__ btP,
        u16* __restrict__ h16, u8* __restrict__ h8, float* __restrict__ stats) {
    __shared__ u16 sA[16 * SROW];
    __shared__ float acS[256];
    int tid = threadIdx.x;
    long nodebase = (long)blockIdx.x * 16;       // 3125*16 == 50000 exact

    if (BN) {
        if (tid < 128) {
            float s = 0.f, qq = 0.f;
            #pragma unroll
            for (int b = 0; b < 8; ++b) {
                s  += statsPrev[b * 512 + tid];
                qq += statsPrev[b * 512 + 256 + tid];
            }
            float mu = s * NINV;
            float var = qq * NINV - mu * mu;
            float a = gP[tid] * rsqrtf(var + 1e-5f);
            acS[tid] = a;
            acS[128 + tid] = btP[tid] - mu * a;
        }
        __syncthreads();
    }

    // ---- phase 1: gather-mean (fp8, 16B/lane, even/odd edge split) ----
    {
        int grp = tid >> 4;          // node 0..15
        int g   = tid & 15;
        int sub = g >> 3;            // 0: even edges, 1: odd edges
        int gl  = g & 7;
        int d16 = gl * 16;           // dim base
        int node = (int)nodebase + grp;
        int s = row_ptr[node], e = row_ptr[node + 1];
        float av[16], ov[16];
        if (BN) {
            #pragma unroll
            for (int k = 0; k < 16; ++k) { av[k] = acS[d16 + k]; ov[k] = acS[128 + d16 + k]; }
        }
        float sum[16];
        #pragma unroll
        for (int k = 0; k < 16; ++k) sum[k] = 0.f;
        int j = s + sub;
        for (; j + 6 < e; j += 8) {
            int i0 = col_src[j], i1 = col_src[j + 2], i2 = col_src[j + 4], i3 = col_src[j + 6];
            u32x4 w0 = *(const u32x4*)(fq + (long)i0 * DIM + d16);
            u32x4 w1 = *(const u32x4*)(fq + (long)i1 * DIM + d16);
            u32x4 w2 = *(const u32x4*)(fq + (long)i2 * DIM + d16);
            u32x4 w3 = *(const u32x4*)(fq + (long)i3 * DIM + d16);
            acc_row16<BN>(w0, sum, av, ov);
            acc_row16<BN>(w1, sum, av, ov);
            acc_row16<BN>(w2, sum, av, ov);
            acc_row16<BN>(w3, sum, av, ov);
        }
        for (; j < e; j += 2) {
            int i0 = col_src[j];
            u32x4 w0 = *(const u32x4*)(fq + (long)i0 * DIM + d16);
            acc_row16<BN>(w0, sum, av, ov);
        }
        // combine even/odd halves
        #pragma unroll
        for (int k = 0; k < 16; ++k) sum[k] += __shfl_xor(sum[k], 8);
        if (sub == 0) {
            float dn = (e > s) ? 1.f / (float)(e - s) : 1.f;
            us8 r0, r1;
            #pragma unroll
            for (int k = 0; k < 8; ++k) {
                r0[k] = f2bf(sum[k] * dn);
                r1[k] = f2bf(sum[8 + k] * dn);
            }
            *(us8*)(sA + grp * SROW + d16) = r0;
            *(us8*)(sA + grp * SROW + d16 + 8) = r1;
        }
    }
    __syncthreads();

    // ---- phase 2: MFMA ----
    int cg = tid >> 6, lane = tid & 63;
    int q = lane >> 4, nn = lane & 15;
    long rc = nodebase + nn;

    short8 ah[8];
    #pragma unroll
    for (int kc = 0; kc < 4; ++kc)
        ah[kc] = *(const short8*)(sA + nn * SROW + kc * 32 + q * 8);
    #pragma unroll
    for (int kc = 0; kc < 4; ++kc) {
        int ko = kc * 32 + q * 8;
        us8 rv = *(const us8*)(fh + rc * DIM + ko);
        short8 t;
        if (BN) {
            #pragma unroll
            for (int j = 0; j < 8; ++j) {
                float v = bf2f(rv[j]) * acS[ko + j] + acS[128 + ko + j];
                t[j] = (short)f2bf(v > 0.f ? v : 0.f);
            }
        } else {
            #pragma unroll
            for (int j = 0; j < 8; ++j) t[j] = (short)rv[j];
        }
        ah[4 + kc] = t;
    }

    f32x4 acc[2];
    acc[0] = (f32x4){0.f, 0.f, 0.f, 0.f};
    acc[1] = (f32x4){0.f, 0.f, 0.f, 0.f};

    #pragma unroll
    for (int kc = 0; kc < 8; ++kc) {
        #pragma unroll
        for (int nt = 0; nt < 2; ++nt) {
            int ntg = cg * 2 + nt;
            short8 bh = *(const short8*)(Bph + (((ntg * 8 + kc) * 64 + lane) << 3));
            acc[nt] = __builtin_amdgcn_mfma_f32_16x16x32_bf16(ah[kc], bh, acc[nt], 0, 0, 0);
        }
    }

    int bank = blockIdx.x & 7;
    #pragma unroll
    for (int nt = 0; nt < 2; ++nt) {
        int col = cg * 32 + nt * 16 + nn;
        float bv = bias[col];
        float ps = 0.f, pq = 0.f;
        #pragma unroll
        for (int r = 0; r < 4; ++r) {
            float v = acc[nt][r] + bv;
            long idx = (nodebase + q * 4 + r) * DIM + col;
            h16[idx] = f2bf(v);
            if (W8) {
                int pb = __builtin_amdgcn_cvt_pk_fp8_f32(v, v, 0, false);
                h8[idx] = (u8)(pb & 0xff);
            }
            ps += v; pq += v * v;
        }
        ps += __shfl_xor(ps, 16);
        ps += __shfl_xor(ps, 32);
        pq += __shfl_xor(pq, 16);
        pq += __shfl_xor(pq, 32);
        if (q == 0) {
            atomicAdd(&stats[bank * 512 + col], ps);
            atomicAdd(&stats[bank * 512 + 256 + col], pq);
        }
    }
}

// out = relu(bn(h)+x); coeffs computed in-block from banked stats
__global__ __launch_bounds__(256) void k_bn_add_relu(
        const u16* __restrict__ h, const float* __restrict__ stats,
        const float* __restrict__ g, const float* __restrict__ bt,
        const float* __restrict__ x, float* __restrict__ outv) {
    __shared__ float acS[256];
    int tid = threadIdx.x;
    if (tid < 128) {
        float s = 0.f, qq = 0.f;
        #pragma unroll
        for (int b = 0; b < 8; ++b) {
            s  += stats[b * 512 + tid];
            qq += stats[b * 512 + 256 + tid];
        }
        float mu = s * NINV;
        float var = qq * NINV - mu * mu;
        float a = g[tid] * rsqrtf(var + 1e-5f);
        acS[tid] = a;
        acS[128 + tid] = bt[tid] - mu * a;
    }
    __syncthreads();
    long i8 = ((long)blockIdx.x * 256 + tid) * 8;
    int c = (int)(i8 & 127);
    us8 hv = *(const us8*)(h + i8);
    f32x4 x0 = *(const f32x4*)(x + i8);
    f32x4 x1 = *(const f32x4*)(x + i8 + 4);
    f32x4 r0, r1;
    #pragma unroll
    for (int j = 0; j < 4; ++j) {
        float v = bf2f(hv[j]) * acS[c + j] + acS[128 + c + j] + x0[j];
        r0[j] = v > 0.f ? v : 0.f;
        float w = bf2f(hv[4 + j]) * acS[c + 4 + j] + acS[128 + c + 4 + j] + x1[j];
        r1[j] = w > 0.f ? w : 0.f;
    }
    *(f32x4*)(outv + i8) = r0;
    *(f32x4*)(outv + i8 + 4) = r1;
}

extern "C" void kernel_launch(void* const* d_in, const int* in_sizes, int n_in,
                              void* d_out, int out_size, void* d_ws, size_t ws_size,
                              hipStream_t stream) {
    (void)in_sizes; (void)n_in; (void)out_size; (void)ws_size;
    const float* x   = (const float*)d_in[0];
    const int*   ei  = (const int*)d_in[1];
    const float* W1l = (const float*)d_in[2];
    const float* b1  = (const float*)d_in[3];
    const float* W1r = (const float*)d_in[4];
    const float* g1  = (const float*)d_in[5];
    const float* bt1 = (const float*)d_in[6];
    const float* W2l = (const float*)d_in[7];
    const float* b2  = (const float*)d_in[8];
    const float* W2r = (const float*)d_in[9];
    const float* g2  = (const float*)d_in[10];
    const float* bt2 = (const float*)d_in[11];
    float* out = (float*)d_out;

    const int* esrc = ei;
    const int* edst = ei + N_EDGES;

    char* ws = (char*)d_ws;
    size_t off = 0;
    auto alloc = [&](size_t bytes) { size_t p = off; off = (off + bytes + 255) & ~(size_t)255; return p; };
    int*   deg     = (int*)  (ws + alloc(N_NODES * 4));
    float* stats1  = (float*)(ws + alloc(4096 * 4));   // 8 banks x 512 (sum@+col, sumsq@+256+col)
    float* stats2  = (float*)(ws + alloc(4096 * 4));
    size_t zero_bytes = off;                       // everything above must be zeroed
    int*   cursor  = (int*)  (ws + alloc(N_NODES * 4));
    int*   row_ptr = (int*)  (ws + alloc((N_NODES + 1) * 4));
    int*   bsum    = (int*)  (ws + alloc(256 * 4));
    int*   bpre    = (int*)  (ws + alloc(256 * 4));
    u16*   col_src = (u16*)  (ws + alloc((size_t)N_EDGES * 2));
    u16*   xh      = (u16*)  (ws + alloc((size_t)N_NODES * DIM * 2));
    u8*    xf8     = (u8*)   (ws + alloc((size_t)N_NODES * DIM));
    u16*   hb1     = (u16*)  (ws + alloc((size_t)N_NODES * DIM * 2));  // raw h1 bf16
    u8*    h1f8    = (u8*)   (ws + alloc((size_t)N_NODES * DIM));     // raw h1 fp8
    u16*   hb2     = (u16*)  (ws + alloc((size_t)N_NODES * DIM * 2));  // raw h2 bf16
    u16*   Bp1h    = (u16*)  (ws + alloc(256 * 128 * 2));
    u16*   Bp2h    = (u16*)  (ws + alloc(256 * 128 * 2));

    hipMemsetAsync(ws, 0, zero_bytes, stream);

    const int EB = (N_EDGES + 255) / 256;            // 3125
    const int FILLB = EB * NPART;                    // 25000
    const int AGB = N_NODES / 16;                    // 3125 exact
    const int EWB4 = (int)(((long)N_NODES * DIM) / 1024);  // 6250 exact
    const int EWB8 = (int)(((long)N_NODES * DIM) / 2048);  // 3125 exact
    const int PREPB = 32 + EWB4 + EB;                // pack + split + hist

    // prep: pack both B + split x (bf16 + fp8) + degree histogram (concurrent)
    k_prep<<<PREPB, 256, 0, stream>>>(W1l, W1r, Bp1h, W2l, W2r, Bp2h, x, xh, xf8,
                                      edst, deg, EWB4);

    // CSR scans + fill
    k_scan1<<<SCAN_B, 256, 0, stream>>>(deg, bsum);
    k_scan2<<<1, 256, 0, stream>>>(bsum, bpre);
    k_scan3<<<SCAN_B, 256, 0, stream>>>(deg, bpre, row_ptr, cursor);
    k_fill<<<FILLB, 256, 0, stream>>>(esrc, edst, cursor, col_src);

    // stage 1: fused agg+gemm on x (fp8 gather, bf16 root); writes h1 bf16 + fp8
    k_ag<0, 1><<<AGB, 256, 0, stream>>>(xf8, xh, row_ptr, col_src, Bp1h, b1,
                                        stats1, g1, bt1, hb1, h1f8, stats1);

    // stage 2: fused agg+gemm on h1 with BN+relu at operand load (coeffs from stats1)
    k_ag<1, 0><<<AGB, 256, 0, stream>>>(h1f8, hb1, row_ptr, col_src, Bp2h, b2,
                                        stats1, g1, bt1, hb2, h1f8, stats2);

    // epilogue: out = relu(bn(h2) + x), coeffs from stats2
    k_bn_add_relu<<<EWB8, 256, 0, stream>>>(hb2, stats2, g2, bt2, x, out);
}